// Round 3
// baseline (4448.024 us; speedup 1.0000x reference)
//
#include <hip/hip_runtime.h>

#define NN   50000
#define DD   128
#define RR   3
#define EE   800000
#define OUTD 64
#define BKT  128                  // nodes per dst bucket
#define NBK  391                  // ceil(NN/BKT)
#define CAP  2560                 // per-bucket edge capacity (mean 2048, +11 sigma)
#define CHUNK 8192                // edges per bin block
#define NCH  98                   // ceil(EE/CHUNK)
#define ALPHA_ 0.5f
#define SLOPE_ 0.01f
#define BETA1_ 0.6931471805599453f   // log(2)
#define BETA2_ 0.4054651081081644f   // log(1.5)

// ---------------- binning: bucket-sort edges by dst>>7 with LDS staging ----------------
__global__ __launch_bounds__(256) void bin_kernel(
    const int* __restrict__ src, const int* __restrict__ dst,
    int* __restrict__ cnt_out, int* __restrict__ bcnt, int* __restrict__ pairs)
{
    __shared__ int hist[NBK];
    __shared__ int lbase[NBK];
    __shared__ int gdelta[NBK];
    __shared__ int lcur[NBK];
    __shared__ int staging[CHUNK];
    __shared__ unsigned short sbuck[CHUNK];
    const int tid = threadIdx.x;
    const int r = blockIdx.x / NCH;
    const int chunk = blockIdx.x % NCH;
    const int e0 = chunk * CHUNK;
    const int n = min(CHUNK, EE - e0);
    const int* sp = src + (size_t)r * EE + e0;
    const int* dp = dst + (size_t)r * EE + e0;

    for (int i = tid; i < NBK; i += 256) hist[i] = 0;
    __syncthreads();
    // histogram + global out-degree count
    for (int i = tid; i < n; i += 256) {
        atomicAdd(&hist[dp[i] >> 7], 1);
        atomicAdd(&cnt_out[r * NN + sp[i]], 1);
    }
    __syncthreads();
    // exclusive scan hist -> lbase (first wave only)
    if (tid < 64) {
        int carry = 0;
        for (int c0 = 0; c0 < NBK; c0 += 64) {
            const int idx = c0 + tid;
            const int v = (idx < NBK) ? hist[idx] : 0;
            int incl = v;
            #pragma unroll
            for (int d = 1; d < 64; d <<= 1) {
                const int t = __shfl_up(incl, d, 64);
                if (tid >= d) incl += t;
            }
            if (idx < NBK) lbase[idx] = carry + incl - v;
            carry += __shfl(incl, 63, 64);
        }
    }
    __syncthreads();
    // reserve global ranges
    for (int b = tid; b < NBK; b += 256) {
        lcur[b] = lbase[b];
        const int h = hist[b];
        if (h > 0) {
            const int gstart = (r * NBK + b) * CAP + atomicAdd(&bcnt[r * NBK + b], h);
            gdelta[b] = gstart - lbase[b];
        }
    }
    __syncthreads();
    // scatter into LDS staging (bucket-sorted)
    for (int i = tid; i < n; i += 256) {
        const int d = dp[i];
        const int b = d >> 7;
        const int pos = atomicAdd(&lcur[b], 1);
        staging[pos] = sp[i] | ((d & 127) << 16);
        sbuck[pos] = (unsigned short)b;
    }
    __syncthreads();
    // coalesced copy-out of runs
    for (int j = tid; j < n; j += 256) {
        const int b = sbuck[j];
        const int gi = gdelta[b] + j;
        const int lo = gi - (r * NBK + b) * CAP;
        if (lo < CAP) pairs[gi] = staging[j];
    }
}

// ---------------- out-degree -> rsqrt norm ----------------
__global__ __launch_bounds__(256) void dego_fin_kernel(
    const int* __restrict__ cnt_out, float* __restrict__ dego_r)
{
    const int i = blockIdx.x * 256 + threadIdx.x;
    if (i < RR * NN) dego_r[i] = rsqrtf((float)max(cnt_out[i], 1));
}

// ---------------- in-degree per bucket from binned pairs ----------------
__global__ __launch_bounds__(128) void degi_kernel(
    const int* __restrict__ pairs, const int* __restrict__ bcnt,
    float* __restrict__ degi_r)
{
    __shared__ int cnt[BKT];
    const int tid = threadIdx.x;
    const int bid = blockIdx.x;            // r*NBK + b
    cnt[tid] = 0;
    __syncthreads();
    const int n = min(bcnt[bid], CAP);
    const int* pp = pairs + (size_t)bid * CAP;
    for (int j = tid; j < n; j += 128)
        atomicAdd(&cnt[pp[j] >> 16], 1);
    __syncthreads();
    const int r = bid / NBK;
    const int g = (bid % NBK) * BKT + tid;
    if (g < NN) degi_r[r * NN + g] = rsqrtf((float)max(cnt[tid], 1));
}

// ---------------- fused layer: aggregate (LDS atomics) + blend + GEMM + mean ----------------
// grid = NBK, block = 1024, LDS = 128KB+. ACT: leaky_relu. LIN: fuse final @Wlin (layer 2).
template<int ACT, int LIN>
__global__ __launch_bounds__(1024) void layer_kernel(
    const float* __restrict__ hsrc,    // gather table [N,128]
    const float* __restrict__ x,       // residual feat0 [N,128]
    const int* __restrict__ pairs, const int* __restrict__ bcnt,
    const float* __restrict__ dego_r, const float* __restrict__ degi_r,
    const float* __restrict__ W,       // [R,128,128]
    const float* __restrict__ bias,    // [R,128]
    const float* __restrict__ Wlin,    // [128,64] (LIN only)
    const float* __restrict__ blin,    // [64]     (LIN only)
    float* __restrict__ hout,          // [N,128] (h1) or [N,64] (out)
    float beta)
{
    __shared__ float acc[BKT * DD];    // 64 KB
    __shared__ float Wl[DD * DD];      // 64 KB
    __shared__ float bl[DD];
    const int tid = threadIdx.x;
    const int c = blockIdx.x;
    const int node0 = c * BKT;
    const int rg = tid >> 5;           // 0..31 row groups (4 rows each)
    const int cg = tid & 31;           // 0..31 col groups (4 cols each)
    const float omb = 1.0f - beta;
    float4* acc4 = (float4*)acc;
    float o[16];
    #pragma unroll
    for (int i = 0; i < 16; ++i) o[i] = 0.f;

    for (int r = 0; r < RR; ++r) {
        __syncthreads();
        for (int i = tid; i < BKT * DD / 4; i += 1024) acc4[i] = make_float4(0.f, 0.f, 0.f, 0.f);
        for (int i = tid; i < DD * DD / 4; i += 1024)
            ((float4*)Wl)[i] = ((const float4*)(W + (size_t)r * DD * DD))[i];
        if (tid < DD) bl[tid] = bias[r * DD + tid];
        __syncthreads();

        // ---- aggregate: 32-lane group per edge, lane-per-bank LDS adds (conflict-free) ----
        const int bid = r * NBK + c;
        const int cnt = min(bcnt[bid], CAP);
        const int* pp = pairs + (size_t)bid * CAP;
        for (int e = rg; e < cnt; e += 32) {
            const int pk = pp[e];
            const int s = pk & 0xFFFF;
            const int dl = pk >> 16;
            const float ns = dego_r[r * NN + s];
            const float* hp = hsrc + (size_t)s * DD + cg;
            float* ap = acc + dl * DD + cg;
            #pragma unroll
            for (int k = 0; k < 4; ++k)
                unsafeAtomicAdd(&ap[32 * k], hp[32 * k] * ns);
        }
        __syncthreads();

        // ---- rst = acc * degi_norm * (1-a) + a * x ----
        for (int i = tid; i < BKT * DD / 4; i += 1024) {
            const int row = i >> 5;
            const int g = node0 + row;
            float4 a = acc4[i];
            if (g < NN) {
                const float nd = degi_r[r * NN + g] * (1.0f - ALPHA_);
                const float4 xv = ((const float4*)x)[(size_t)g * 32 + (i & 31)];
                a.x = a.x * nd + ALPHA_ * xv.x;
                a.y = a.y * nd + ALPHA_ * xv.y;
                a.z = a.z * nd + ALPHA_ * xv.z;
                a.w = a.w * nd + ALPHA_ * xv.w;
            } else {
                a = make_float4(0.f, 0.f, 0.f, 0.f);
            }
            acc4[i] = a;
        }
        __syncthreads();

        // ---- GEMM 128x128 @ 128x128 from LDS, 4 rows x 4 cols per thread ----
        float4 ra[4];
        #pragma unroll
        for (int j = 0; j < 4; ++j) ra[j] = make_float4(0.f, 0.f, 0.f, 0.f);
        #pragma unroll 4
        for (int k = 0; k < DD; ++k) {
            const float4 w = ((const float4*)(Wl + k * DD))[cg];
            #pragma unroll
            for (int j = 0; j < 4; ++j) {
                const float xj = acc[(4 * rg + j) * DD + k];
                ra[j].x = fmaf(xj, w.x, ra[j].x);
                ra[j].y = fmaf(xj, w.y, ra[j].y);
                ra[j].z = fmaf(xj, w.z, ra[j].z);
                ra[j].w = fmaf(xj, w.w, ra[j].w);
            }
        }
        // ---- epilogue: (1-b)rst + b*(rst@W) + bias [+leaky], mean-accumulate ----
        const float4 bb = ((const float4*)bl)[cg];
        #pragma unroll
        for (int j = 0; j < 4; ++j) {
            const float4 rv = ((const float4*)(acc + (4 * rg + j) * DD))[cg];
            float4 v;
            v.x = omb * rv.x + beta * ra[j].x + bb.x;
            v.y = omb * rv.y + beta * ra[j].y + bb.y;
            v.z = omb * rv.z + beta * ra[j].z + bb.z;
            v.w = omb * rv.w + beta * ra[j].w + bb.w;
            if (ACT) {
                v.x = v.x >= 0.f ? v.x : SLOPE_ * v.x;
                v.y = v.y >= 0.f ? v.y : SLOPE_ * v.y;
                v.z = v.z >= 0.f ? v.z : SLOPE_ * v.z;
                v.w = v.w >= 0.f ? v.w : SLOPE_ * v.w;
            }
            o[4 * j + 0] += v.x * (1.f / 3.f);
            o[4 * j + 1] += v.y * (1.f / 3.f);
            o[4 * j + 2] += v.z * (1.f / 3.f);
            o[4 * j + 3] += v.w * (1.f / 3.f);
        }
    }

    if (!LIN) {
        #pragma unroll
        for (int j = 0; j < 4; ++j) {
            const int g = node0 + 4 * rg + j;
            if (g < NN)
                ((float4*)(hout + (size_t)g * DD))[cg] =
                    make_float4(o[4 * j], o[4 * j + 1], o[4 * j + 2], o[4 * j + 3]);
        }
    } else {
        // ---- fused final linear: h2 rows -> acc, GEMM with Wlin, write out [N,64] ----
        __syncthreads();
        #pragma unroll
        for (int j = 0; j < 4; ++j)
            ((float4*)(acc + (4 * rg + j) * DD))[cg] =
                make_float4(o[4 * j], o[4 * j + 1], o[4 * j + 2], o[4 * j + 3]);
        for (int i = tid; i < DD * OUTD / 4; i += 1024)
            ((float4*)Wl)[i] = ((const float4*)Wlin)[i];
        if (tid < OUTD) bl[tid] = blin[tid];
        __syncthreads();

        const int rg2 = tid >> 4;          // 0..63 -> 2 rows each
        const int cg2 = tid & 15;          // 0..15 -> 4 cols each
        const int r0 = 2 * rg2, r1 = r0 + 1;
        float4 a0 = make_float4(0.f, 0.f, 0.f, 0.f);
        float4 a1 = make_float4(0.f, 0.f, 0.f, 0.f);
        #pragma unroll 4
        for (int k = 0; k < DD; ++k) {
            const float4 w = ((const float4*)(Wl + k * OUTD))[cg2];
            const float x0 = acc[r0 * DD + k];
            const float x1 = acc[r1 * DD + k];
            a0.x = fmaf(x0, w.x, a0.x); a0.y = fmaf(x0, w.y, a0.y);
            a0.z = fmaf(x0, w.z, a0.z); a0.w = fmaf(x0, w.w, a0.w);
            a1.x = fmaf(x1, w.x, a1.x); a1.y = fmaf(x1, w.y, a1.y);
            a1.z = fmaf(x1, w.z, a1.z); a1.w = fmaf(x1, w.w, a1.w);
        }
        const float4 bb = ((const float4*)bl)[cg2];
        const int g0 = node0 + r0, g1 = node0 + r1;
        if (g0 < NN)
            ((float4*)(hout + (size_t)g0 * OUTD))[cg2] =
                make_float4(a0.x + bb.x, a0.y + bb.y, a0.z + bb.z, a0.w + bb.w);
        if (g1 < NN)
            ((float4*)(hout + (size_t)g1 * OUTD))[cg2] =
                make_float4(a1.x + bb.x, a1.y + bb.y, a1.z + bb.z, a1.w + bb.w);
    }
}

extern "C" void kernel_launch(void* const* d_in, const int* in_sizes, int n_in,
                              void* d_out, int out_size, void* d_ws, size_t ws_size,
                              hipStream_t stream)
{
    const float* x    = (const float*)d_in[0];
    const int*   src  = (const int*)  d_in[1];
    const int*   dst  = (const int*)  d_in[2];
    const float* W1   = (const float*)d_in[3];
    const float* b1   = (const float*)d_in[4];
    const float* W2   = (const float*)d_in[5];
    const float* b2   = (const float*)d_in[6];
    const float* Wlin = (const float*)d_in[7];
    const float* blin = (const float*)d_in[8];
    float* out = (float*)d_out;

    // ws layout (4B units): cnt_out[3N] | dego_r[3N] | degi_r[3N] | bcnt[3*NBK] |
    //                       pairs[3*NBK*CAP] | h1[N*D]                     ~= 40 MB
    int*   cnt_out = (int*)d_ws;
    float* dego_r  = (float*)(cnt_out + RR * NN);
    float* degi_r  = dego_r + RR * NN;
    int*   bcnt    = (int*)(degi_r + RR * NN);
    int*   pairs   = bcnt + RR * NBK;
    float* h1      = (float*)(pairs + (size_t)RR * NBK * CAP);

    hipMemsetAsync(cnt_out, 0, (size_t)RR * NN * sizeof(int), stream);
    hipMemsetAsync(bcnt,    0, (size_t)RR * NBK * sizeof(int), stream);

    bin_kernel<<<RR * NCH, 256, 0, stream>>>(src, dst, cnt_out, bcnt, pairs);
    dego_fin_kernel<<<(RR * NN + 255) / 256, 256, 0, stream>>>(cnt_out, dego_r);
    degi_kernel<<<RR * NBK, 128, 0, stream>>>(pairs, bcnt, degi_r);

    layer_kernel<1, 0><<<NBK, 1024, 0, stream>>>(
        x, x, pairs, bcnt, dego_r, degi_r, W1, b1, nullptr, nullptr, h1, BETA1_);
    layer_kernel<0, 1><<<NBK, 1024, 0, stream>>>(
        h1, x, pairs, bcnt, dego_r, degi_r, W2, b2, Wlin, blin, out, BETA2_);
}

// Round 4
// 812.446 us; speedup vs baseline: 5.4749x; 5.4749x over previous
//
#include <hip/hip_runtime.h>

#define NN   50000
#define DD   128
#define RR   3
#define EE   800000
#define OUTD 64
#define BKT  128                  // nodes per dst bucket
#define NBK  391                  // ceil(NN/BKT)
#define CAP  2560                 // per-bucket edge capacity (mean 2048, +11 sigma)
#define CHUNK 8192                // edges per bin block
#define NCH  98                   // ceil(EE/CHUNK)
#define ALPHA_ 0.5f
#define SLOPE_ 0.01f
#define BETA1_ 0.6931471805599453f   // log(2)
#define BETA2_ 0.4054651081081644f   // log(1.5)

typedef unsigned int   uint32;
typedef unsigned short ushort16;

__device__ __forceinline__ unsigned short f2b(float f) {   // fp32 -> bf16 RNE
    unsigned int u = __builtin_bit_cast(unsigned int, f);
    u += 0x7FFFu + ((u >> 16) & 1u);
    return (unsigned short)(u >> 16);
}
__device__ __forceinline__ float blo(unsigned int w) { return __builtin_bit_cast(float, w << 16); }
__device__ __forceinline__ float bhi(unsigned int w) { return __builtin_bit_cast(float, w & 0xFFFF0000u); }

// ---------------- binning: bucket-sort edges by dst>>7 with LDS staging ----------------
__global__ __launch_bounds__(256) void bin_kernel(
    const int* __restrict__ src, const int* __restrict__ dst,
    int* __restrict__ cnt_out, int* __restrict__ bcnt, int* __restrict__ pairs)
{
    __shared__ int hist[NBK];
    __shared__ int lbase[NBK];
    __shared__ int gdelta[NBK];
    __shared__ int lcur[NBK];
    __shared__ int staging[CHUNK];
    __shared__ unsigned short sbuck[CHUNK];
    const int tid = threadIdx.x;
    const int r = blockIdx.x / NCH;
    const int chunk = blockIdx.x % NCH;
    const int e0 = chunk * CHUNK;
    const int n = min(CHUNK, EE - e0);
    const int* sp = src + (size_t)r * EE + e0;
    const int* dp = dst + (size_t)r * EE + e0;

    for (int i = tid; i < NBK; i += 256) hist[i] = 0;
    __syncthreads();
    for (int i = tid; i < n; i += 256) {
        atomicAdd(&hist[dp[i] >> 7], 1);
        atomicAdd(&cnt_out[r * NN + sp[i]], 1);
    }
    __syncthreads();
    if (tid < 64) {
        int carry = 0;
        for (int c0 = 0; c0 < NBK; c0 += 64) {
            const int idx = c0 + tid;
            const int v = (idx < NBK) ? hist[idx] : 0;
            int incl = v;
            #pragma unroll
            for (int d = 1; d < 64; d <<= 1) {
                const int t = __shfl_up(incl, d, 64);
                if (tid >= d) incl += t;
            }
            if (idx < NBK) lbase[idx] = carry + incl - v;
            carry += __shfl(incl, 63, 64);
        }
    }
    __syncthreads();
    for (int b = tid; b < NBK; b += 256) {
        lcur[b] = lbase[b];
        const int h = hist[b];
        if (h > 0) {
            const int gstart = (r * NBK + b) * CAP + atomicAdd(&bcnt[r * NBK + b], h);
            gdelta[b] = gstart - lbase[b];
        }
    }
    __syncthreads();
    for (int i = tid; i < n; i += 256) {
        const int d = dp[i];
        const int b = d >> 7;
        const int pos = atomicAdd(&lcur[b], 1);
        staging[pos] = sp[i] | ((d & 127) << 16);
        sbuck[pos] = (unsigned short)b;
    }
    __syncthreads();
    for (int j = tid; j < n; j += 256) {
        const int b = sbuck[j];
        const int gi = gdelta[b] + j;
        const int lo = gi - (r * NBK + b) * CAP;
        if (lo < CAP) pairs[gi] = staging[j];
    }
}

// ---------------- out-degree -> rsqrt norm ----------------
__global__ __launch_bounds__(256) void dego_fin_kernel(
    const int* __restrict__ cnt_out, float* __restrict__ dego_r)
{
    const int i = blockIdx.x * 256 + threadIdx.x;
    if (i < RR * NN) dego_r[i] = rsqrtf((float)max(cnt_out[i], 1));
}

// ---------------- per-bucket counting sort (in-place) -> CSR + off + cnt + degi ----------------
__global__ __launch_bounds__(256) void bucket_sort_kernel(
    int* __restrict__ pairs, const int* __restrict__ bcnt,
    int* __restrict__ off_g, int* __restrict__ cnt_g, float* __restrict__ degi_r)
{
    __shared__ int stage[CAP];
    __shared__ int cnt[BKT];
    __shared__ int base[BKT];
    __shared__ int pos[BKT];
    const int tid = threadIdx.x;
    const int bid = blockIdx.x;              // r*NBK + b
    const int n = min(bcnt[bid], CAP);
    int* pp = pairs + (size_t)bid * CAP;
    if (tid < BKT) cnt[tid] = 0;
    __syncthreads();
    for (int i = tid; i < n; i += 256) {
        const int p = pp[i];
        stage[i] = p;
        atomicAdd(&cnt[p >> 16], 1);
    }
    __syncthreads();
    if (tid < 64) {
        int carry = 0;
        for (int c0 = 0; c0 < BKT; c0 += 64) {
            const int v = cnt[c0 + tid];
            int incl = v;
            #pragma unroll
            for (int d = 1; d < 64; d <<= 1) {
                const int t = __shfl_up(incl, d, 64);
                if (tid >= d) incl += t;
            }
            base[c0 + tid] = carry + incl - v;
            carry += __shfl(incl, 63, 64);
        }
    }
    __syncthreads();
    if (tid < BKT) {
        pos[tid] = base[tid];
        const int r = bid / NBK;
        const int g = (bid % NBK) * BKT + tid;
        if (g < NN) {
            off_g[r * NN + g] = bid * CAP + base[tid];
            cnt_g[r * NN + g] = cnt[tid];
            degi_r[r * NN + g] = rsqrtf((float)max(cnt[tid], 1));
        }
    }
    __syncthreads();
    for (int i = tid; i < n; i += 256) {
        const int p = stage[i];
        const int q = atomicAdd(&pos[p >> 16], 1);
        pp[q] = p & 0xFFFF;                  // src index only (fits 16 bits)
    }
}

// ---------------- cast fp32 -> bf16 table ----------------
__global__ __launch_bounds__(256) void cast_kernel(
    const float* __restrict__ x, unsigned short* __restrict__ xb)
{
    const int i = blockIdx.x * 256 + threadIdx.x;
    if (i >= NN * DD / 4) return;
    const float4 v = ((const float4*)x)[i];
    ushort4 o;
    o.x = f2b(v.x); o.y = f2b(v.y); o.z = f2b(v.z); o.w = f2b(v.w);
    ((ushort4*)xb)[i] = o;
}

// ---------------- pull aggregation (bf16 gather) + dst-normalize + residual ----------------
// 16 lanes per dst node, 16B (8 bf16) per lane per edge. No atomics.
__global__ __launch_bounds__(256) void pull_kernel(
    const unsigned short* __restrict__ hb, const float* __restrict__ x,
    const int* __restrict__ csr, const int* __restrict__ off_g,
    const int* __restrict__ cnt_g, const float* __restrict__ dego_r,
    const float* __restrict__ degi_r, float* __restrict__ agg)
{
    const int tid = blockIdx.x * 256 + threadIdx.x;
    const int node = tid >> 4;
    if (node >= NN) return;
    const int lane = tid & 15;
    const int j0 = off_g[node];
    const int j1 = j0 + cnt_g[node];
    const uint4* hb4 = (const uint4*)hb;
    float a0 = 0.f, a1 = 0.f, a2 = 0.f, a3 = 0.f, a4 = 0.f, a5 = 0.f, a6 = 0.f, a7 = 0.f;
    int j = j0;
    for (; j + 2 <= j1; j += 2) {
        const int s0 = csr[j], s1 = csr[j + 1];
        const float n0 = dego_r[s0], n1 = dego_r[s1];
        const uint4 q0 = hb4[(size_t)s0 * 16 + lane];
        const uint4 q1 = hb4[(size_t)s1 * 16 + lane];
        a0 += blo(q0.x) * n0 + blo(q1.x) * n1;
        a1 += bhi(q0.x) * n0 + bhi(q1.x) * n1;
        a2 += blo(q0.y) * n0 + blo(q1.y) * n1;
        a3 += bhi(q0.y) * n0 + bhi(q1.y) * n1;
        a4 += blo(q0.z) * n0 + blo(q1.z) * n1;
        a5 += bhi(q0.z) * n0 + bhi(q1.z) * n1;
        a6 += blo(q0.w) * n0 + blo(q1.w) * n1;
        a7 += bhi(q0.w) * n0 + bhi(q1.w) * n1;
    }
    if (j < j1) {
        const int s0 = csr[j];
        const float n0 = dego_r[s0];
        const uint4 q0 = hb4[(size_t)s0 * 16 + lane];
        a0 += blo(q0.x) * n0; a1 += bhi(q0.x) * n0;
        a2 += blo(q0.y) * n0; a3 += bhi(q0.y) * n0;
        a4 += blo(q0.z) * n0; a5 += bhi(q0.z) * n0;
        a6 += blo(q0.w) * n0; a7 += bhi(q0.w) * n0;
    }
    const float nd = degi_r[node] * (1.0f - ALPHA_);
    const float4* x4 = (const float4*)(x + (size_t)node * DD);
    const float4 x0 = x4[2 * lane], x1 = x4[2 * lane + 1];
    float4* o4 = (float4*)(agg + (size_t)node * DD);
    o4[2 * lane]     = make_float4(a0 * nd + ALPHA_ * x0.x, a1 * nd + ALPHA_ * x0.y,
                                   a2 * nd + ALPHA_ * x0.z, a3 * nd + ALPHA_ * x0.w);
    o4[2 * lane + 1] = make_float4(a4 * nd + ALPHA_ * x1.x, a5 * nd + ALPHA_ * x1.y,
                                   a6 * nd + ALPHA_ * x1.z, a7 * nd + ALPHA_ * x1.w);
}

// ---------------- GEMM [N,128]@[128,128] + identity-map epilogue + mean-accum ----------------
// MODE 0: write fp32 (first relation). MODE 1: RMW fp32. MODE 2: read fp32, write bf16.
template<int ACT, int MODE>
__global__ __launch_bounds__(256) void gemm_ep_kernel(
    const float* __restrict__ rst, const float* __restrict__ W,
    const float* __restrict__ b, float* __restrict__ hout_f,
    unsigned short* __restrict__ hout_b, float beta)
{
    __shared__ float Wl[DD * DD];       // 64 KB
    __shared__ float rowbuf[16][DD];    // 8 KB
    __shared__ float bl[DD];
    const int tid = threadIdx.x;
    for (int i = tid; i < DD * DD / 4; i += 256)
        ((float4*)Wl)[i] = ((const float4*)W)[i];
    if (tid < DD) bl[tid] = b[tid];
    const int lane = tid & 31;
    const int ty = tid >> 5;            // 0..7
    const int r0 = ty * 2, r1 = r0 + 1;
    const float omb = 1.0f - beta;
    const int blockRow = blockIdx.x * 64;

    for (int it = 0; it < 4; ++it) {
        const int rb = blockRow + it * 16;
        __syncthreads();
        for (int i = tid; i < 16 * DD / 4; i += 256) {
            const int rr = i >> 5, cc = i & 31;
            const int grow = rb + rr;
            float4 v = make_float4(0.f, 0.f, 0.f, 0.f);
            if (grow < NN) v = ((const float4*)(rst + (size_t)grow * DD))[cc];
            ((float4*)rowbuf)[i] = v;
        }
        __syncthreads();

        float4 a0 = make_float4(0.f, 0.f, 0.f, 0.f);
        float4 a1 = make_float4(0.f, 0.f, 0.f, 0.f);
        for (int k = 0; k < DD; ++k) {
            const float4 w = ((const float4*)(Wl + k * DD))[lane];
            const float x0 = rowbuf[r0][k];
            const float x1 = rowbuf[r1][k];
            a0.x = fmaf(x0, w.x, a0.x); a0.y = fmaf(x0, w.y, a0.y);
            a0.z = fmaf(x0, w.z, a0.z); a0.w = fmaf(x0, w.w, a0.w);
            a1.x = fmaf(x1, w.x, a1.x); a1.y = fmaf(x1, w.y, a1.y);
            a1.z = fmaf(x1, w.z, a1.z); a1.w = fmaf(x1, w.w, a1.w);
        }

        const float4 bb = ((const float4*)bl)[lane];
        #pragma unroll
        for (int p = 0; p < 2; ++p) {
            const int rr = (p == 0) ? r0 : r1;
            const float4 ac = (p == 0) ? a0 : a1;
            const int grow = rb + rr;
            if (grow < NN) {
                const float4 rv = ((const float4*)rowbuf[rr])[lane];
                float4 v;
                v.x = omb * rv.x + beta * ac.x + bb.x;
                v.y = omb * rv.y + beta * ac.y + bb.y;
                v.z = omb * rv.z + beta * ac.z + bb.z;
                v.w = omb * rv.w + beta * ac.w + bb.w;
                if (ACT) {
                    v.x = v.x >= 0.f ? v.x : SLOPE_ * v.x;
                    v.y = v.y >= 0.f ? v.y : SLOPE_ * v.y;
                    v.z = v.z >= 0.f ? v.z : SLOPE_ * v.z;
                    v.w = v.w >= 0.f ? v.w : SLOPE_ * v.w;
                }
                v.x *= (1.0f / 3.0f); v.y *= (1.0f / 3.0f);
                v.z *= (1.0f / 3.0f); v.w *= (1.0f / 3.0f);
                if (MODE == 0) {
                    ((float4*)(hout_f + (size_t)grow * DD))[lane] = v;
                } else {
                    float4* hf = (float4*)(hout_f + (size_t)grow * DD) + lane;
                    const float4 prev = *hf;
                    v.x += prev.x; v.y += prev.y; v.z += prev.z; v.w += prev.w;
                    if (MODE == 1) {
                        *hf = v;
                    } else {
                        ushort4 ob;
                        ob.x = f2b(v.x); ob.y = f2b(v.y);
                        ob.z = f2b(v.z); ob.w = f2b(v.w);
                        ((ushort4*)(hout_b + (size_t)grow * DD))[lane] = ob;
                    }
                }
            }
        }
    }
}

// ---------------- final linear [N,128]@[128,64] + bias ----------------
__global__ __launch_bounds__(256) void lin_kernel(
    const float* __restrict__ h, const float* __restrict__ Wlin,
    const float* __restrict__ blin, float* __restrict__ out)
{
    __shared__ float Wl[DD * OUTD];     // 32 KB
    __shared__ float rowbuf[16][DD];    // 8 KB
    __shared__ float bl[OUTD];
    const int tid = threadIdx.x;
    for (int i = tid; i < DD * OUTD / 4; i += 256)
        ((float4*)Wl)[i] = ((const float4*)Wlin)[i];
    if (tid < OUTD) bl[tid] = blin[tid];
    const int lane = tid & 15;
    const int ty = tid >> 4;
    const int blockRow = blockIdx.x * 64;

    for (int it = 0; it < 4; ++it) {
        const int rb = blockRow + it * 16;
        __syncthreads();
        for (int i = tid; i < 16 * DD / 4; i += 256) {
            const int rr = i >> 5, cc = i & 31;
            const int grow = rb + rr;
            float4 v = make_float4(0.f, 0.f, 0.f, 0.f);
            if (grow < NN) v = ((const float4*)(h + (size_t)grow * DD))[cc];
            ((float4*)rowbuf)[i] = v;
        }
        __syncthreads();

        float4 acc = make_float4(0.f, 0.f, 0.f, 0.f);
        for (int k = 0; k < DD; ++k) {
            const float4 w = ((const float4*)(Wl + k * OUTD))[lane];
            const float xv = rowbuf[ty][k];
            acc.x = fmaf(xv, w.x, acc.x);
            acc.y = fmaf(xv, w.y, acc.y);
            acc.z = fmaf(xv, w.z, acc.z);
            acc.w = fmaf(xv, w.w, acc.w);
        }
        const int grow = rb + ty;
        if (grow < NN) {
            const float4 bb = ((const float4*)bl)[lane];
            ((float4*)(out + (size_t)grow * OUTD))[lane] =
                make_float4(acc.x + bb.x, acc.y + bb.y, acc.z + bb.z, acc.w + bb.w);
        }
    }
}

extern "C" void kernel_launch(void* const* d_in, const int* in_sizes, int n_in,
                              void* d_out, int out_size, void* d_ws, size_t ws_size,
                              hipStream_t stream)
{
    const float* x    = (const float*)d_in[0];
    const int*   src  = (const int*)  d_in[1];
    const int*   dst  = (const int*)  d_in[2];
    const float* W1   = (const float*)d_in[3];
    const float* b1   = (const float*)d_in[4];
    const float* W2   = (const float*)d_in[5];
    const float* b2   = (const float*)d_in[6];
    const float* Wlin = (const float*)d_in[7];
    const float* blin = (const float*)d_in[8];
    float* out = (float*)d_out;

    // ws layout (4B units): cnt_out[3N] | dego_r[3N] | degi_r[3N] | off_g[3N] | cnt_g[3N] |
    //   bcnt[3*NBK] | pairs[3*NBK*CAP] | xb(bf16 N*D /2) | h1b(bf16 N*D /2) |
    //   agg[N*D] | h1[N*D] | h2[N*D]                                  ~= 107 MB
    int*   cnt_out = (int*)d_ws;
    float* dego_r  = (float*)(cnt_out + RR * NN);
    float* degi_r  = dego_r + RR * NN;
    int*   off_g   = (int*)(degi_r + RR * NN);
    int*   cnt_g   = off_g + RR * NN;
    int*   bcnt    = cnt_g + RR * NN;
    int*   pairs   = bcnt + RR * NBK;
    unsigned short* xb  = (unsigned short*)(pairs + (size_t)RR * NBK * CAP);
    unsigned short* h1b = xb + (size_t)NN * DD;
    float* agg     = (float*)(h1b + (size_t)NN * DD);
    float* h1      = agg + (size_t)NN * DD;
    float* h2      = h1  + (size_t)NN * DD;

    hipMemsetAsync(cnt_out, 0, (size_t)RR * NN * sizeof(int), stream);
    hipMemsetAsync(bcnt,    0, (size_t)RR * NBK * sizeof(int), stream);

    const int pull_blocks = (NN * 16 + 255) / 256;
    const int gemm_blocks = (NN + 63) / 64;

    // ---- graph preprocessing (once; same graph both layers) ----
    bin_kernel<<<RR * NCH, 256, 0, stream>>>(src, dst, cnt_out, bcnt, pairs);
    dego_fin_kernel<<<(RR * NN + 255) / 256, 256, 0, stream>>>(cnt_out, dego_r);
    bucket_sort_kernel<<<RR * NBK, 256, 0, stream>>>(pairs, bcnt, off_g, cnt_g, degi_r);
    cast_kernel<<<(NN * DD / 4 + 255) / 256, 256, 0, stream>>>(x, xb);

    // ---- conv1: h1b(bf16) = mean_r gcn2(x, x, W1_r, b1_r, beta1, leaky) ----
    for (int r = 0; r < RR; ++r) {
        pull_kernel<<<pull_blocks, 256, 0, stream>>>(
            xb, x, pairs, off_g + r * NN, cnt_g + r * NN,
            dego_r + r * NN, degi_r + r * NN, agg);
        if (r == 0)
            gemm_ep_kernel<1, 0><<<gemm_blocks, 256, 0, stream>>>(
                agg, W1, b1, h1, nullptr, BETA1_);
        else if (r == 1)
            gemm_ep_kernel<1, 1><<<gemm_blocks, 256, 0, stream>>>(
                agg, W1 + (size_t)1 * DD * DD, b1 + 1 * DD, h1, nullptr, BETA1_);
        else
            gemm_ep_kernel<1, 2><<<gemm_blocks, 256, 0, stream>>>(
                agg, W1 + (size_t)2 * DD * DD, b1 + 2 * DD, h1, h1b, BETA1_);
    }
    // ---- conv2: h2 = mean_r gcn2(h1, x, W2_r, b2_r, beta2, no act) ----
    for (int r = 0; r < RR; ++r) {
        pull_kernel<<<pull_blocks, 256, 0, stream>>>(
            h1b, x, pairs, off_g + r * NN, cnt_g + r * NN,
            dego_r + r * NN, degi_r + r * NN, agg);
        if (r == 0)
            gemm_ep_kernel<0, 0><<<gemm_blocks, 256, 0, stream>>>(
                agg, W2, b2, h2, nullptr, BETA2_);
        else
            gemm_ep_kernel<0, 1><<<gemm_blocks, 256, 0, stream>>>(
                agg, W2 + (size_t)r * DD * DD, b2 + r * DD, h2, nullptr, BETA2_);
    }
    // ---- final linear ----
    lin_kernel<<<gemm_blocks, 256, 0, stream>>>(h2, Wlin, blin, out);
}

// Round 5
// 778.875 us; speedup vs baseline: 5.7108x; 1.0431x over previous
//
#include <hip/hip_runtime.h>

#define NN    50000
#define DD    128
#define RR    3
#define EE    800000
#define OUTD  64
#define BKT   128                 // nodes per dst bucket
#define NBK   391                 // ceil(NN/BKT)
#define CAP   2560                // per-bucket edge capacity (mean 2048, +11 sigma)
#define CHUNK 4096                // edges per bin block (30KB LDS -> 5 blocks/CU)
#define NCH   196                 // ceil(EE/CHUNK)
#define NPB   3125                // NN/16 pull blocks per relation
#define ALPHA_ 0.5f
#define SLOPE_ 0.01f
#define BETA1_ 0.6931471805599453f   // log(2)
#define BETA2_ 0.4054651081081644f   // log(1.5)

__device__ __forceinline__ unsigned short f2b(float f) {   // fp32 -> bf16 RNE
    unsigned int u = __builtin_bit_cast(unsigned int, f);
    u += 0x7FFFu + ((u >> 16) & 1u);
    return (unsigned short)(u >> 16);
}
__device__ __forceinline__ unsigned int pack2(float lo, float hi) {
    return (unsigned int)f2b(lo) | ((unsigned int)f2b(hi) << 16);
}
__device__ __forceinline__ float blo(unsigned int w) { return __builtin_bit_cast(float, w << 16); }
__device__ __forceinline__ float bhi(unsigned int w) { return __builtin_bit_cast(float, w & 0xFFFF0000u); }

// ---------------- binning: bucket-sort edges by dst>>7 with LDS staging ----------------
__global__ __launch_bounds__(256) void bin_kernel(
    const int* __restrict__ src, const int* __restrict__ dst,
    int* __restrict__ cnt_out, int* __restrict__ bcnt, int* __restrict__ pairs)
{
    __shared__ int hist[NBK];
    __shared__ int lbase[NBK];
    __shared__ int gdelta[NBK];
    __shared__ int lcur[NBK];
    __shared__ int staging[CHUNK];
    __shared__ unsigned short sbuck[CHUNK];
    const int tid = threadIdx.x;
    const int r = blockIdx.x / NCH;
    const int chunk = blockIdx.x % NCH;
    const int e0 = chunk * CHUNK;
    const int n = min(CHUNK, EE - e0);
    const int* sp = src + (size_t)r * EE + e0;
    const int* dp = dst + (size_t)r * EE + e0;

    for (int i = tid; i < NBK; i += 256) hist[i] = 0;
    __syncthreads();
    for (int i = tid; i < n; i += 256) {
        atomicAdd(&hist[dp[i] >> 7], 1);
        atomicAdd(&cnt_out[r * NN + sp[i]], 1);
    }
    __syncthreads();
    if (tid < 64) {
        int carry = 0;
        for (int c0 = 0; c0 < NBK; c0 += 64) {
            const int idx = c0 + tid;
            const int v = (idx < NBK) ? hist[idx] : 0;
            int incl = v;
            #pragma unroll
            for (int d = 1; d < 64; d <<= 1) {
                const int t = __shfl_up(incl, d, 64);
                if (tid >= d) incl += t;
            }
            if (idx < NBK) lbase[idx] = carry + incl - v;
            carry += __shfl(incl, 63, 64);
        }
    }
    __syncthreads();
    for (int b = tid; b < NBK; b += 256) {
        lcur[b] = lbase[b];
        const int h = hist[b];
        if (h > 0) {
            const int gstart = (r * NBK + b) * CAP + atomicAdd(&bcnt[r * NBK + b], h);
            gdelta[b] = gstart - lbase[b];
        }
    }
    __syncthreads();
    for (int i = tid; i < n; i += 256) {
        const int d = dp[i];
        const int b = d >> 7;
        const int pos = atomicAdd(&lcur[b], 1);
        staging[pos] = sp[i] | ((d & 127) << 16);
        sbuck[pos] = (unsigned short)b;
    }
    __syncthreads();
    for (int j = tid; j < n; j += 256) {
        const int b = sbuck[j];
        const int gi = gdelta[b] + j;
        const int lo = gi - (r * NBK + b) * CAP;
        if (lo < CAP) pairs[gi] = staging[j];
    }
}

// ---------------- out-degree -> rsqrt norm ----------------
__global__ __launch_bounds__(256) void dego_fin_kernel(
    const int* __restrict__ cnt_out, float* __restrict__ dego_r)
{
    const int i = blockIdx.x * 256 + threadIdx.x;
    if (i < RR * NN) dego_r[i] = rsqrtf((float)max(cnt_out[i], 1));
}

// ---------------- per-bucket counting sort (in-place) -> CSR + off + cnt + degi ----------------
__global__ __launch_bounds__(256) void bucket_sort_kernel(
    int* __restrict__ pairs, const int* __restrict__ bcnt,
    int* __restrict__ off_g, int* __restrict__ cnt_g, float* __restrict__ degi_r)
{
    __shared__ int stage[CAP];
    __shared__ int cnt[BKT];
    __shared__ int base[BKT];
    __shared__ int pos[BKT];
    const int tid = threadIdx.x;
    const int bid = blockIdx.x;              // r*NBK + b
    const int n = min(bcnt[bid], CAP);
    int* pp = pairs + (size_t)bid * CAP;
    if (tid < BKT) cnt[tid] = 0;
    __syncthreads();
    for (int i = tid; i < n; i += 256) {
        const int p = pp[i];
        stage[i] = p;
        atomicAdd(&cnt[p >> 16], 1);
    }
    __syncthreads();
    if (tid < 64) {
        int carry = 0;
        for (int c0 = 0; c0 < BKT; c0 += 64) {
            const int v = cnt[c0 + tid];
            int incl = v;
            #pragma unroll
            for (int d = 1; d < 64; d <<= 1) {
                const int t = __shfl_up(incl, d, 64);
                if (tid >= d) incl += t;
            }
            base[c0 + tid] = carry + incl - v;
            carry += __shfl(incl, 63, 64);
        }
    }
    __syncthreads();
    if (tid < BKT) {
        pos[tid] = base[tid];
        const int r = bid / NBK;
        const int g = (bid % NBK) * BKT + tid;
        if (g < NN) {
            off_g[r * NN + g] = bid * CAP + base[tid];
            cnt_g[r * NN + g] = cnt[tid];
            degi_r[r * NN + g] = rsqrtf((float)max(cnt[tid], 1));
        }
    }
    __syncthreads();
    for (int i = tid; i < n; i += 256) {
        const int p = stage[i];
        const int q = atomicAdd(&pos[p >> 16], 1);
        pp[q] = p & 0xFFFF;                  // src index only (fits 16 bits)
    }
}

// ---------------- cast fp32 -> bf16 table ----------------
__global__ __launch_bounds__(256) void cast_kernel(
    const float* __restrict__ x, unsigned short* __restrict__ xb)
{
    const int i = blockIdx.x * 256 + threadIdx.x;
    if (i >= NN * DD / 4) return;
    const float4 v = ((const float4*)x)[i];
    ushort4 o;
    o.x = f2b(v.x); o.y = f2b(v.y); o.z = f2b(v.z); o.w = f2b(v.w);
    ((ushort4*)xb)[i] = o;
}

// ---------------- merged pull (all 3 relations): bf16 gather + normalize + residual ----------------
// 16 lanes per dst node (16B = 8 bf16 each). Output aggb[r][node][128] bf16.
__global__ __launch_bounds__(256) void pull_all_kernel(
    const unsigned short* __restrict__ hb,   // gather table [N,128] bf16
    const unsigned short* __restrict__ xb,   // residual [N,128] bf16
    const int* __restrict__ pairs, const int* __restrict__ off_g,
    const int* __restrict__ cnt_g, const float* __restrict__ dego_r,
    const float* __restrict__ degi_r, unsigned short* __restrict__ aggb)
{
    const int blk = blockIdx.x;              // r*NPB + nb
    const int r = blk / NPB;
    const int node = (blk % NPB) * 16 + (threadIdx.x >> 4);
    const int lane = threadIdx.x & 15;
    const int gi = r * NN + node;
    const int j0 = off_g[gi];
    const int j1 = j0 + cnt_g[gi];
    const float* dego = dego_r + (size_t)r * NN;
    const uint4* hb4 = (const uint4*)hb;
    float a0 = 0.f, a1 = 0.f, a2 = 0.f, a3 = 0.f, a4 = 0.f, a5 = 0.f, a6 = 0.f, a7 = 0.f;
    int j = j0;
    for (; j + 2 <= j1; j += 2) {
        const int s0 = pairs[j], s1 = pairs[j + 1];
        const float n0 = dego[s0], n1 = dego[s1];
        const uint4 q0 = hb4[(size_t)s0 * 16 + lane];
        const uint4 q1 = hb4[(size_t)s1 * 16 + lane];
        a0 += blo(q0.x) * n0 + blo(q1.x) * n1;
        a1 += bhi(q0.x) * n0 + bhi(q1.x) * n1;
        a2 += blo(q0.y) * n0 + blo(q1.y) * n1;
        a3 += bhi(q0.y) * n0 + bhi(q1.y) * n1;
        a4 += blo(q0.z) * n0 + blo(q1.z) * n1;
        a5 += bhi(q0.z) * n0 + bhi(q1.z) * n1;
        a6 += blo(q0.w) * n0 + blo(q1.w) * n1;
        a7 += bhi(q0.w) * n0 + bhi(q1.w) * n1;
    }
    if (j < j1) {
        const int s0 = pairs[j];
        const float n0 = dego[s0];
        const uint4 q0 = hb4[(size_t)s0 * 16 + lane];
        a0 += blo(q0.x) * n0; a1 += bhi(q0.x) * n0;
        a2 += blo(q0.y) * n0; a3 += bhi(q0.y) * n0;
        a4 += blo(q0.z) * n0; a5 += bhi(q0.z) * n0;
        a6 += blo(q0.w) * n0; a7 += bhi(q0.w) * n0;
    }
    const float nd = degi_r[gi] * (1.0f - ALPHA_);
    const uint4 xq = ((const uint4*)xb)[(size_t)node * 16 + lane];
    uint4 o;
    o.x = pack2(a0 * nd + ALPHA_ * blo(xq.x), a1 * nd + ALPHA_ * bhi(xq.x));
    o.y = pack2(a2 * nd + ALPHA_ * blo(xq.y), a3 * nd + ALPHA_ * bhi(xq.y));
    o.z = pack2(a4 * nd + ALPHA_ * blo(xq.z), a5 * nd + ALPHA_ * bhi(xq.z));
    o.w = pack2(a6 * nd + ALPHA_ * blo(xq.w), a7 * nd + ALPHA_ * bhi(xq.w));
    ((uint4*)aggb)[(size_t)gi * 16 + lane] = o;
}

// ---------------- fused conv: 3-relation GEMM + epilogue + mean; optional @Wlin fusion ----------------
// 64 rows/block, r-loop in-kernel with W_r staged to LDS; accumulators o[4][8] in VGPRs.
// LIN=0: write h1b bf16. LIN=1: park h2 tile in LDS (padded stride 129), GEMM with Wlin, write out.
template<int ACT, int LIN>
__global__ __launch_bounds__(256) void conv_kernel(
    const unsigned short* __restrict__ aggb,   // [R][N][128] bf16
    const float* __restrict__ W,               // [R,128,128]
    const float* __restrict__ bias,            // [R,128]
    const float* __restrict__ Wlin,            // [128,64] (LIN)
    const float* __restrict__ blin,            // [64]     (LIN)
    unsigned short* __restrict__ houtb,        // h1b (LIN=0)
    float* __restrict__ outf,                  // out (LIN=1)
    float beta)
{
    __shared__ float Wl[64 * 129 + DD * OUTD]; // 64.2KB: W-stage (16384) | reused as h2t(64x129)+Wlin(8192)
    __shared__ float rowbuf[16][DD];           // 8 KB
    __shared__ float bl[DD];
    const int tid = threadIdx.x;
    const int lane = tid & 31;
    const int ty = tid >> 5;                   // 0..7
    const int r0 = 2 * ty, r1 = r0 + 1;
    const float omb = 1.0f - beta;
    const int blockRow = blockIdx.x * 64;
    float o[4][8];
    #pragma unroll
    for (int a = 0; a < 4; ++a)
        #pragma unroll
        for (int c = 0; c < 8; ++c) o[a][c] = 0.f;

    for (int r = 0; r < RR; ++r) {
        __syncthreads();
        for (int i = tid; i < DD * DD / 4; i += 256)
            ((float4*)Wl)[i] = ((const float4*)(W + (size_t)r * DD * DD))[i];
        if (tid < DD) bl[tid] = bias[r * DD + tid];
        __syncthreads();

        for (int it = 0; it < 4; ++it) {
            // stage 16 rows of aggb (bf16 -> fp32)
            {
                const int rr = tid >> 4, cc = tid & 15;
                const int grow = blockRow + it * 16 + rr;
                uint4 q = make_uint4(0, 0, 0, 0);
                if (grow < NN)
                    q = ((const uint4*)aggb)[((size_t)r * NN + grow) * 16 + cc];
                float* rbp = &rowbuf[rr][cc * 8];
                rbp[0] = blo(q.x); rbp[1] = bhi(q.x);
                rbp[2] = blo(q.y); rbp[3] = bhi(q.y);
                rbp[4] = blo(q.z); rbp[5] = bhi(q.z);
                rbp[6] = blo(q.w); rbp[7] = bhi(q.w);
            }
            __syncthreads();

            float4 a0 = make_float4(0.f, 0.f, 0.f, 0.f);
            float4 a1 = make_float4(0.f, 0.f, 0.f, 0.f);
            for (int k = 0; k < DD; ++k) {
                const float4 w = ((const float4*)(Wl + k * DD))[lane];
                const float x0 = rowbuf[r0][k];
                const float x1 = rowbuf[r1][k];
                a0.x = fmaf(x0, w.x, a0.x); a0.y = fmaf(x0, w.y, a0.y);
                a0.z = fmaf(x0, w.z, a0.z); a0.w = fmaf(x0, w.w, a0.w);
                a1.x = fmaf(x1, w.x, a1.x); a1.y = fmaf(x1, w.y, a1.y);
                a1.z = fmaf(x1, w.z, a1.z); a1.w = fmaf(x1, w.w, a1.w);
            }

            const float4 bb = ((const float4*)bl)[lane];
            #pragma unroll
            for (int p = 0; p < 2; ++p) {
                const float4 ac = (p == 0) ? a0 : a1;
                const float4 rv = ((const float4*)(&rowbuf[(p == 0) ? r0 : r1][0]))[lane];
                float4 v;
                v.x = omb * rv.x + beta * ac.x + bb.x;
                v.y = omb * rv.y + beta * ac.y + bb.y;
                v.z = omb * rv.z + beta * ac.z + bb.z;
                v.w = omb * rv.w + beta * ac.w + bb.w;
                if (ACT) {
                    v.x = v.x >= 0.f ? v.x : SLOPE_ * v.x;
                    v.y = v.y >= 0.f ? v.y : SLOPE_ * v.y;
                    v.z = v.z >= 0.f ? v.z : SLOPE_ * v.z;
                    v.w = v.w >= 0.f ? v.w : SLOPE_ * v.w;
                }
                o[it][p * 4 + 0] += v.x * (1.f / 3.f);
                o[it][p * 4 + 1] += v.y * (1.f / 3.f);
                o[it][p * 4 + 2] += v.z * (1.f / 3.f);
                o[it][p * 4 + 3] += v.w * (1.f / 3.f);
            }
            __syncthreads();
        }
    }

    if (!LIN) {
        #pragma unroll
        for (int it = 0; it < 4; ++it) {
            #pragma unroll
            for (int p = 0; p < 2; ++p) {
                const int grow = blockRow + it * 16 + 2 * ty + p;
                if (grow < NN) {
                    ushort4 ob;
                    ob.x = f2b(o[it][p * 4 + 0]); ob.y = f2b(o[it][p * 4 + 1]);
                    ob.z = f2b(o[it][p * 4 + 2]); ob.w = f2b(o[it][p * 4 + 3]);
                    ((ushort4*)(houtb + (size_t)grow * DD))[lane] = ob;
                }
            }
        }
    } else {
        // park h2 tile (64 x 128, stride 129) in Wl; then GEMM with Wlin
        float* h2t = Wl;
        float* Wll = Wl + 64 * 129;
        #pragma unroll
        for (int it = 0; it < 4; ++it) {
            #pragma unroll
            for (int p = 0; p < 2; ++p) {
                const int lrow = it * 16 + 2 * ty + p;
                float* hp = h2t + lrow * 129 + 4 * lane;
                hp[0] = o[it][p * 4 + 0]; hp[1] = o[it][p * 4 + 1];
                hp[2] = o[it][p * 4 + 2]; hp[3] = o[it][p * 4 + 3];
            }
        }
        for (int i = tid; i < DD * OUTD / 4; i += 256)
            ((float4*)Wll)[i] = ((const float4*)Wlin)[i];
        if (tid < OUTD) bl[tid] = blin[tid];
        __syncthreads();

        const int ty2 = tid >> 4;            // 0..15 -> 4 rows each
        const int cg2 = tid & 15;            // 0..15 -> 4 cols each
        float4 acc[4];
        #pragma unroll
        for (int jj = 0; jj < 4; ++jj) acc[jj] = make_float4(0.f, 0.f, 0.f, 0.f);
        #pragma unroll 4
        for (int k = 0; k < DD; ++k) {
            const float4 w = ((const float4*)(Wll + k * OUTD))[cg2];
            #pragma unroll
            for (int jj = 0; jj < 4; ++jj) {
                const float xv = h2t[(4 * ty2 + jj) * 129 + k];
                acc[jj].x = fmaf(xv, w.x, acc[jj].x);
                acc[jj].y = fmaf(xv, w.y, acc[jj].y);
                acc[jj].z = fmaf(xv, w.z, acc[jj].z);
                acc[jj].w = fmaf(xv, w.w, acc[jj].w);
            }
        }
        const float4 bb = ((const float4*)bl)[cg2];
        #pragma unroll
        for (int jj = 0; jj < 4; ++jj) {
            const int g = blockRow + 4 * ty2 + jj;
            if (g < NN)
                ((float4*)(outf + (size_t)g * OUTD))[cg2] =
                    make_float4(acc[jj].x + bb.x, acc[jj].y + bb.y,
                                acc[jj].z + bb.z, acc[jj].w + bb.w);
        }
    }
}

extern "C" void kernel_launch(void* const* d_in, const int* in_sizes, int n_in,
                              void* d_out, int out_size, void* d_ws, size_t ws_size,
                              hipStream_t stream)
{
    const float* x    = (const float*)d_in[0];
    const int*   src  = (const int*)  d_in[1];
    const int*   dst  = (const int*)  d_in[2];
    const float* W1   = (const float*)d_in[3];
    const float* b1   = (const float*)d_in[4];
    const float* W2   = (const float*)d_in[5];
    const float* b2   = (const float*)d_in[6];
    const float* Wlin = (const float*)d_in[7];
    const float* blin = (const float*)d_in[8];
    float* out = (float*)d_out;

    // ws layout (4B units): cnt_out[3N] | dego_r[3N] | degi_r[3N] | off_g[3N] | cnt_g[3N] |
    //   bcnt[3*NBK] | pairs[3*NBK*CAP] | xb(bf16, N*D/2) | h1b(bf16, N*D/2) |
    //   aggb(bf16, 3*N*D/2)                                          ~= 80 MB
    int*   cnt_out = (int*)d_ws;
    float* dego_r  = (float*)(cnt_out + RR * NN);
    float* degi_r  = dego_r + RR * NN;
    int*   off_g   = (int*)(degi_r + RR * NN);
    int*   cnt_g   = off_g + RR * NN;
    int*   bcnt    = cnt_g + RR * NN;
    int*   pairs   = bcnt + RR * NBK;
    unsigned short* xb   = (unsigned short*)(pairs + (size_t)RR * NBK * CAP);
    unsigned short* h1b  = xb + (size_t)NN * DD;
    unsigned short* aggb = h1b + (size_t)NN * DD;

    hipMemsetAsync(cnt_out, 0, (size_t)RR * NN * sizeof(int), stream);
    hipMemsetAsync(bcnt,    0, (size_t)RR * NBK * sizeof(int), stream);

    const int gemm_blocks = (NN + 63) / 64;

    // ---- graph preprocessing (once; same graph both layers) ----
    bin_kernel<<<RR * NCH, 256, 0, stream>>>(src, dst, cnt_out, bcnt, pairs);
    dego_fin_kernel<<<(RR * NN + 255) / 256, 256, 0, stream>>>(cnt_out, dego_r);
    bucket_sort_kernel<<<RR * NBK, 256, 0, stream>>>(pairs, bcnt, off_g, cnt_g, degi_r);
    cast_kernel<<<(NN * DD / 4 + 255) / 256, 256, 0, stream>>>(x, xb);

    // ---- conv1: h1b = bf16( mean_r gcn2(x, x, W1_r, b1_r, beta1, leaky) ) ----
    pull_all_kernel<<<RR * NPB, 256, 0, stream>>>(
        xb, xb, pairs, off_g, cnt_g, dego_r, degi_r, aggb);
    conv_kernel<1, 0><<<gemm_blocks, 256, 0, stream>>>(
        aggb, W1, b1, nullptr, nullptr, h1b, nullptr, BETA1_);

    // ---- conv2 (+ fused final linear): out = (mean_r gcn2(h1, x, ...)) @ Wlin + blin ----
    pull_all_kernel<<<RR * NPB, 256, 0, stream>>>(
        h1b, xb, pairs, off_g, cnt_g, dego_r, degi_r, aggb);
    conv_kernel<0, 1><<<gemm_blocks, 256, 0, stream>>>(
        aggb, W2, b2, Wlin, blin, nullptr, out, BETA2_);
}

// Round 6
// 487.800 us; speedup vs baseline: 9.1185x; 1.5967x over previous
//
#include <hip/hip_runtime.h>

#define NN    50000
#define DD    128
#define RR    3
#define EE    800000
#define OUTD  64
#define BKT   128                 // nodes per dst bucket
#define NBK   391                 // ceil(NN/BKT)
#define CAP   2560                // per-bucket edge capacity (mean 2048, +11 sigma)
#define CHUNK 4096                // edges per bin block (30KB LDS -> 5 blocks/CU)
#define NCH   196                 // ceil(EE/CHUNK)
#define NPB   3125                // NN/16 pull blocks per relation
#define ALPHA_ 0.5f
#define SLOPE_ 0.01f
#define BETA1_ 0.6931471805599453f   // log(2)
#define BETA2_ 0.4054651081081644f   // log(1.5)

typedef __attribute__((ext_vector_type(8))) short short8;   // 8 bf16 = 4 VGPRs
typedef __attribute__((ext_vector_type(4))) float f32x4;

__device__ __forceinline__ unsigned short f2b(float f) {   // fp32 -> bf16 RNE
    unsigned int u = __builtin_bit_cast(unsigned int, f);
    u += 0x7FFFu + ((u >> 16) & 1u);
    return (unsigned short)(u >> 16);
}
__device__ __forceinline__ unsigned int pack2(float lo, float hi) {
    return (unsigned int)f2b(lo) | ((unsigned int)f2b(hi) << 16);
}
__device__ __forceinline__ float blo(unsigned int w) { return __builtin_bit_cast(float, w << 16); }
__device__ __forceinline__ float bhi(unsigned int w) { return __builtin_bit_cast(float, w & 0xFFFF0000u); }

// ---------------- binning: bucket-sort edges by dst>>7 with LDS staging ----------------
__global__ __launch_bounds__(256) void bin_kernel(
    const int* __restrict__ src, const int* __restrict__ dst,
    int* __restrict__ cnt_out, int* __restrict__ bcnt, int* __restrict__ pairs)
{
    __shared__ int hist[NBK];
    __shared__ int lbase[NBK];
    __shared__ int gdelta[NBK];
    __shared__ int lcur[NBK];
    __shared__ int staging[CHUNK];
    __shared__ unsigned short sbuck[CHUNK];
    const int tid = threadIdx.x;
    const int r = blockIdx.x / NCH;
    const int chunk = blockIdx.x % NCH;
    const int e0 = chunk * CHUNK;
    const int n = min(CHUNK, EE - e0);
    const int* sp = src + (size_t)r * EE + e0;
    const int* dp = dst + (size_t)r * EE + e0;

    for (int i = tid; i < NBK; i += 256) hist[i] = 0;
    __syncthreads();
    for (int i = tid; i < n; i += 256) {
        atomicAdd(&hist[dp[i] >> 7], 1);
        atomicAdd(&cnt_out[r * NN + sp[i]], 1);
    }
    __syncthreads();
    if (tid < 64) {
        int carry = 0;
        for (int c0 = 0; c0 < NBK; c0 += 64) {
            const int idx = c0 + tid;
            const int v = (idx < NBK) ? hist[idx] : 0;
            int incl = v;
            #pragma unroll
            for (int d = 1; d < 64; d <<= 1) {
                const int t = __shfl_up(incl, d, 64);
                if (tid >= d) incl += t;
            }
            if (idx < NBK) lbase[idx] = carry + incl - v;
            carry += __shfl(incl, 63, 64);
        }
    }
    __syncthreads();
    for (int b = tid; b < NBK; b += 256) {
        lcur[b] = lbase[b];
        const int h = hist[b];
        if (h > 0) {
            const int gstart = (r * NBK + b) * CAP + atomicAdd(&bcnt[r * NBK + b], h);
            gdelta[b] = gstart - lbase[b];
        }
    }
    __syncthreads();
    for (int i = tid; i < n; i += 256) {
        const int d = dp[i];
        const int b = d >> 7;
        const int pos = atomicAdd(&lcur[b], 1);
        staging[pos] = sp[i] | ((d & 127) << 16);
        sbuck[pos] = (unsigned short)b;
    }
    __syncthreads();
    for (int j = tid; j < n; j += 256) {
        const int b = sbuck[j];
        const int gi = gdelta[b] + j;
        const int lo = gi - (r * NBK + b) * CAP;
        if (lo < CAP) pairs[gi] = staging[j];
    }
}

// ---------------- out-degree -> rsqrt norm ----------------
__global__ __launch_bounds__(256) void dego_fin_kernel(
    const int* __restrict__ cnt_out, float* __restrict__ dego_r)
{
    const int i = blockIdx.x * 256 + threadIdx.x;
    if (i < RR * NN) dego_r[i] = rsqrtf((float)max(cnt_out[i], 1));
}

// ---------------- per-bucket counting sort (in-place) -> CSR + off + cnt + degi ----------------
__global__ __launch_bounds__(256) void bucket_sort_kernel(
    int* __restrict__ pairs, const int* __restrict__ bcnt,
    int* __restrict__ off_g, int* __restrict__ cnt_g, float* __restrict__ degi_r)
{
    __shared__ int stage[CAP];
    __shared__ int cnt[BKT];
    __shared__ int base[BKT];
    __shared__ int pos[BKT];
    const int tid = threadIdx.x;
    const int bid = blockIdx.x;              // r*NBK + b
    const int n = min(bcnt[bid], CAP);
    int* pp = pairs + (size_t)bid * CAP;
    if (tid < BKT) cnt[tid] = 0;
    __syncthreads();
    for (int i = tid; i < n; i += 256) {
        const int p = pp[i];
        stage[i] = p;
        atomicAdd(&cnt[p >> 16], 1);
    }
    __syncthreads();
    if (tid < 64) {
        int carry = 0;
        for (int c0 = 0; c0 < BKT; c0 += 64) {
            const int v = cnt[c0 + tid];
            int incl = v;
            #pragma unroll
            for (int d = 1; d < 64; d <<= 1) {
                const int t = __shfl_up(incl, d, 64);
                if (tid >= d) incl += t;
            }
            base[c0 + tid] = carry + incl - v;
            carry += __shfl(incl, 63, 64);
        }
    }
    __syncthreads();
    if (tid < BKT) {
        pos[tid] = base[tid];
        const int r = bid / NBK;
        const int g = (bid % NBK) * BKT + tid;
        if (g < NN) {
            off_g[r * NN + g] = bid * CAP + base[tid];
            cnt_g[r * NN + g] = cnt[tid];
            degi_r[r * NN + g] = rsqrtf((float)max(cnt[tid], 1));
        }
    }
    __syncthreads();
    for (int i = tid; i < n; i += 256) {
        const int p = stage[i];
        const int q = atomicAdd(&pos[p >> 16], 1);
        pp[q] = p & 0xFFFF;                  // src index only (fits 16 bits)
    }
}

// ---------------- cast fp32 -> bf16 table ----------------
__global__ __launch_bounds__(256) void cast_kernel(
    const float* __restrict__ x, unsigned short* __restrict__ xb)
{
    const int i = blockIdx.x * 256 + threadIdx.x;
    if (i >= NN * DD / 4) return;
    const float4 v = ((const float4*)x)[i];
    ushort4 o;
    o.x = f2b(v.x); o.y = f2b(v.y); o.z = f2b(v.z); o.w = f2b(v.w);
    ((ushort4*)xb)[i] = o;
}

// ---------------- prep: W' = beta*W + (1-beta)I, transposed [n][k], bf16 ----------------
// Wt2 additionally folds the 1/3 relation-mean. WlinT = Wlin^T bf16.
__global__ __launch_bounds__(256) void prep_kernel(
    const float* __restrict__ W1, const float* __restrict__ W2,
    const float* __restrict__ Wlin, unsigned short* __restrict__ Wt1,
    unsigned short* __restrict__ Wt2, unsigned short* __restrict__ WlT)
{
    const int i = blockIdx.x * 256 + threadIdx.x;
    if (i < RR * DD * DD) {
        const int r = i >> 14, rem = i & 16383, n = rem >> 7, k = rem & 127;
        const float diag = (k == n) ? 1.0f : 0.0f;
        const float w1 = W1[r * DD * DD + k * DD + n];
        Wt1[i] = f2b(BETA1_ * w1 + diag * (1.0f - BETA1_));
        const float w2 = W2[r * DD * DD + k * DD + n];
        Wt2[i] = f2b((BETA2_ * w2 + diag * (1.0f - BETA2_)) * (1.0f / 3.0f));
    } else if (i < RR * DD * DD + OUTD * DD) {
        const int j = i - RR * DD * DD;
        const int n = j >> 7, k = j & 127;
        WlT[j] = f2b(Wlin[k * OUTD + n]);
    }
}

// ---------------- merged pull (all 3 relations): bf16 gather + normalize + residual ----------------
__global__ __launch_bounds__(256) void pull_all_kernel(
    const unsigned short* __restrict__ hb,   // gather table [N,128] bf16
    const unsigned short* __restrict__ xb,   // residual [N,128] bf16
    const int* __restrict__ pairs, const int* __restrict__ off_g,
    const int* __restrict__ cnt_g, const float* __restrict__ dego_r,
    const float* __restrict__ degi_r, unsigned short* __restrict__ aggb)
{
    const int blk = blockIdx.x;              // r*NPB + nb
    const int r = blk / NPB;
    const int node = (blk % NPB) * 16 + (threadIdx.x >> 4);
    const int lane = threadIdx.x & 15;
    const int gi = r * NN + node;
    const int j0 = off_g[gi];
    const int j1 = j0 + cnt_g[gi];
    const float* dego = dego_r + (size_t)r * NN;
    const uint4* hb4 = (const uint4*)hb;
    float a0 = 0.f, a1 = 0.f, a2 = 0.f, a3 = 0.f, a4 = 0.f, a5 = 0.f, a6 = 0.f, a7 = 0.f;
    int j = j0;
    for (; j + 2 <= j1; j += 2) {
        const int s0 = pairs[j], s1 = pairs[j + 1];
        const float n0 = dego[s0], n1 = dego[s1];
        const uint4 q0 = hb4[(size_t)s0 * 16 + lane];
        const uint4 q1 = hb4[(size_t)s1 * 16 + lane];
        a0 += blo(q0.x) * n0 + blo(q1.x) * n1;
        a1 += bhi(q0.x) * n0 + bhi(q1.x) * n1;
        a2 += blo(q0.y) * n0 + blo(q1.y) * n1;
        a3 += bhi(q0.y) * n0 + bhi(q1.y) * n1;
        a4 += blo(q0.z) * n0 + blo(q1.z) * n1;
        a5 += bhi(q0.z) * n0 + bhi(q1.z) * n1;
        a6 += blo(q0.w) * n0 + blo(q1.w) * n1;
        a7 += bhi(q0.w) * n0 + bhi(q1.w) * n1;
    }
    if (j < j1) {
        const int s0 = pairs[j];
        const float n0 = dego[s0];
        const uint4 q0 = hb4[(size_t)s0 * 16 + lane];
        a0 += blo(q0.x) * n0; a1 += bhi(q0.x) * n0;
        a2 += blo(q0.y) * n0; a3 += bhi(q0.y) * n0;
        a4 += blo(q0.z) * n0; a5 += bhi(q0.z) * n0;
        a6 += blo(q0.w) * n0; a7 += bhi(q0.w) * n0;
    }
    const float nd = degi_r[gi] * (1.0f - ALPHA_);
    const uint4 xq = ((const uint4*)xb)[(size_t)node * 16 + lane];
    uint4 o;
    o.x = pack2(a0 * nd + ALPHA_ * blo(xq.x), a1 * nd + ALPHA_ * bhi(xq.x));
    o.y = pack2(a2 * nd + ALPHA_ * blo(xq.y), a3 * nd + ALPHA_ * bhi(xq.y));
    o.z = pack2(a4 * nd + ALPHA_ * blo(xq.z), a5 * nd + ALPHA_ * bhi(xq.z));
    o.w = pack2(a6 * nd + ALPHA_ * blo(xq.w), a7 * nd + ALPHA_ * bhi(xq.w));
    ((uint4*)aggb)[(size_t)gi * 16 + lane] = o;
}

// ---------------- MFMA conv: rst_r @ W'_r (+bias-init) [+leaky] summed over r ----------------
// Block = 256 (4 waves); wave computes 16 rows x 128 cols via mfma_f32_16x16x32_bf16.
// A-frags direct from global aggb (16B row segments); B from LDS (stride 136 -> 2-way = free).
// LIN=0: leaky per relation, mean, write h1b bf16 via LDS transpose (coalesced).
// LIN=1: one accumulator (1/3 folded in Wt2), then fused @Wlin via LDS round-trip.
template<int LIN>
__global__ __launch_bounds__(256) void conv_mfma_kernel(
    const unsigned short* __restrict__ aggb,   // [R][N][128] bf16
    const unsigned short* __restrict__ WtG,    // [R][128][128] bf16, [n][k]
    const float* __restrict__ bias,            // [R,128]
    const unsigned short* __restrict__ WlT,    // [64][128] bf16 (LIN)
    const float* __restrict__ blin,            // [64] (LIN)
    unsigned short* __restrict__ houtb,        // h1b (LIN=0)
    float* __restrict__ outf)                  // out [N,64] (LIN=1)
{
    __shared__ unsigned short WtL[DD * 136];   // 34816 B, stride 136 bf16 (17 uint4)
    uint4* WtL4 = (uint4*)WtL;
    const int tid  = threadIdx.x;
    const int wave = tid >> 6;
    const int lane = tid & 63;
    const int l15  = lane & 15;
    const int q    = lane >> 4;                // 0..3
    const int blockRow = blockIdx.x * 64;
    const int row0 = blockRow + wave * 16;
    const int arow = min(row0 + l15, NN - 1);  // A-frag row (clamped; OOB rows not stored)

    f32x4 o[8];
    if (LIN) {
        #pragma unroll
        for (int ct = 0; ct < 8; ++ct) {
            const int col = ct * 16 + l15;
            const float bv = (bias[col] + bias[DD + col] + bias[2 * DD + col]) * (1.0f / 3.0f);
            o[ct] = (f32x4){bv, bv, bv, bv};
        }
    } else {
        #pragma unroll
        for (int ct = 0; ct < 8; ++ct) o[ct] = (f32x4){0.f, 0.f, 0.f, 0.f};
    }

    for (int r = 0; r < RR; ++r) {
        __syncthreads();
        const uint4* wg = (const uint4*)(WtG + (size_t)r * DD * DD);
        for (int i = tid; i < DD * 16; i += 256)
            WtL4[(i >> 4) * 17 + (i & 15)] = wg[i];
        __syncthreads();

        // A-frags: lane holds A[m=l15][k=q*8+j] -> 16B global load per k-step
        short8 a[4];
        const uint4* ap = (const uint4*)aggb + ((size_t)r * NN + arow) * 16 + q;
        #pragma unroll
        for (int ks = 0; ks < 4; ++ks)
            a[ks] = __builtin_bit_cast(short8, ap[ks * 4]);

        #pragma unroll
        for (int ct = 0; ct < 8; ++ct) {
            f32x4 acc;
            if (LIN) {
                acc = o[ct];
            } else {
                const float bv = bias[r * DD + ct * 16 + l15];
                acc = (f32x4){bv, bv, bv, bv};
            }
            const int nrow = ct * 16 + l15;
            #pragma unroll
            for (int ks = 0; ks < 4; ++ks) {
                const short8 b = __builtin_bit_cast(short8, WtL4[nrow * 17 + ks * 4 + q]);
                acc = __builtin_amdgcn_mfma_f32_16x16x32_bf16(a[ks], b, acc, 0, 0, 0);
            }
            if (LIN) {
                o[ct] = acc;
            } else {
                #pragma unroll
                for (int e = 0; e < 4; ++e) {
                    float v = acc[e];
                    v = v >= 0.f ? v : SLOPE_ * v;
                    o[ct][e] += v * (1.0f / 3.0f);
                }
            }
        }
    }

    // park result tile (64 rows x 128 cols, bf16, stride 136) in WtL
    __syncthreads();
    unsigned short* tile = WtL;                // rows 0..63
    #pragma unroll
    for (int ct = 0; ct < 8; ++ct) {
        const int col = ct * 16 + l15;
        #pragma unroll
        for (int e = 0; e < 4; ++e) {
            const int lrow = wave * 16 + q * 4 + e;
            tile[lrow * 136 + col] = f2b(o[ct][e]);
        }
    }
    if (LIN) {                                 // stage WlinT into rows 64..127 region
        uint4* wl4 = WtL4 + 64 * 17;
        const uint4* wg = (const uint4*)WlT;
        for (int i = tid; i < OUTD * 16; i += 256)
            wl4[(i >> 4) * 17 + (i & 15)] = wg[i];
    }
    __syncthreads();

    if (!LIN) {
        // coalesced copy-out: h1b[grow][*] <- tile
        for (int i = tid; i < 64 * 16; i += 256) {
            const int lrow = i >> 4, c = i & 15;
            const int grow = blockRow + lrow;
            if (grow < NN)
                ((uint4*)houtb)[(size_t)grow * 16 + c] = WtL4[lrow * 17 + c];
        }
    } else {
        // second GEMM: out[16x64 per wave] = tile @ Wlin + blin
        short8 a2[4];
        const int lrow = wave * 16 + l15;
        #pragma unroll
        for (int ks = 0; ks < 4; ++ks)
            a2[ks] = __builtin_bit_cast(short8, WtL4[lrow * 17 + ks * 4 + q]);
        #pragma unroll
        for (int ct = 0; ct < 4; ++ct) {
            const int col = ct * 16 + l15;
            const float bv = blin[col];
            f32x4 acc = (f32x4){bv, bv, bv, bv};
            #pragma unroll
            for (int ks = 0; ks < 4; ++ks) {
                const short8 b = __builtin_bit_cast(short8, WtL4[(64 + col) * 17 + ks * 4 + q]);
                acc = __builtin_amdgcn_mfma_f32_16x16x32_bf16(a2[ks], b, acc, 0, 0, 0);
            }
            #pragma unroll
            for (int e = 0; e < 4; ++e) {
                const int grow = row0 + q * 4 + e;
                if (grow < NN) outf[(size_t)grow * OUTD + col] = acc[e];
            }
        }
    }
}

extern "C" void kernel_launch(void* const* d_in, const int* in_sizes, int n_in,
                              void* d_out, int out_size, void* d_ws, size_t ws_size,
                              hipStream_t stream)
{
    const float* x    = (const float*)d_in[0];
    const int*   src  = (const int*)  d_in[1];
    const int*   dst  = (const int*)  d_in[2];
    const float* W1   = (const float*)d_in[3];
    const float* b1   = (const float*)d_in[4];
    const float* W2   = (const float*)d_in[5];
    const float* b2   = (const float*)d_in[6];
    const float* Wlin = (const float*)d_in[7];
    const float* blin = (const float*)d_in[8];
    float* out = (float*)d_out;

    // ws layout (4B units): cnt_out[3N] | dego_r[3N] | degi_r[3N] | off_g[3N] | cnt_g[3N] |
    //   bcnt[3*NBK] | pairs[3*NBK*CAP] | xb(bf16 N*D) | h1b(bf16 N*D) | aggb(bf16 3*N*D) |
    //   Wt1(bf16 3*D*D) | Wt2(bf16 3*D*D) | WlT(bf16 64*D)                 ~= 80 MB
    int*   cnt_out = (int*)d_ws;
    float* dego_r  = (float*)(cnt_out + RR * NN);
    float* degi_r  = dego_r + RR * NN;
    int*   off_g   = (int*)(degi_r + RR * NN);
    int*   cnt_g   = off_g + RR * NN;
    int*   bcnt    = cnt_g + RR * NN;
    int*   pairs   = bcnt + RR * NBK;
    unsigned short* xb   = (unsigned short*)(pairs + (size_t)RR * NBK * CAP);
    unsigned short* h1b  = xb + (size_t)NN * DD;
    unsigned short* aggb = h1b + (size_t)NN * DD;
    unsigned short* Wt1  = aggb + (size_t)RR * NN * DD;
    unsigned short* Wt2  = Wt1 + RR * DD * DD;
    unsigned short* WlT  = Wt2 + RR * DD * DD;

    hipMemsetAsync(cnt_out, 0, (size_t)RR * NN * sizeof(int), stream);
    hipMemsetAsync(bcnt,    0, (size_t)RR * NBK * sizeof(int), stream);

    const int gemm_blocks = (NN + 63) / 64;

    // ---- graph preprocessing (once; same graph both layers) ----
    bin_kernel<<<RR * NCH, 256, 0, stream>>>(src, dst, cnt_out, bcnt, pairs);
    dego_fin_kernel<<<(RR * NN + 255) / 256, 256, 0, stream>>>(cnt_out, dego_r);
    bucket_sort_kernel<<<RR * NBK, 256, 0, stream>>>(pairs, bcnt, off_g, cnt_g, degi_r);
    cast_kernel<<<(NN * DD / 4 + 255) / 256, 256, 0, stream>>>(x, xb);
    prep_kernel<<<(RR * DD * DD + OUTD * DD + 255) / 256, 256, 0, stream>>>(
        W1, W2, Wlin, Wt1, Wt2, WlT);

    // ---- conv1: h1b = bf16( mean_r leaky( rst_r @ W1'_r + b1_r ) ) ----
    pull_all_kernel<<<RR * NPB, 256, 0, stream>>>(
        xb, xb, pairs, off_g, cnt_g, dego_r, degi_r, aggb);
    conv_mfma_kernel<0><<<gemm_blocks, 256, 0, stream>>>(
        aggb, Wt1, b1, nullptr, nullptr, h1b, nullptr);

    // ---- conv2 (+ fused final linear): out = ( sum_r rst_r @ (W2'_r/3) + mean b2 ) @ Wlin + blin ----
    pull_all_kernel<<<RR * NPB, 256, 0, stream>>>(
        h1b, xb, pairs, off_g, cnt_g, dego_r, degi_r, aggb);
    conv_mfma_kernel<1><<<gemm_blocks, 256, 0, stream>>>(
        aggb, Wt2, b2, WlT, blin, nullptr, out);
}

// Round 7
// 473.345 us; speedup vs baseline: 9.3970x; 1.0305x over previous
//
#include <hip/hip_runtime.h>

#define NN    50000
#define DD    128
#define RR    3
#define EE    800000
#define OUTD  64
#define BKT   128                 // nodes per dst bucket
#define NBK   391                 // ceil(NN/BKT)
#define CAP   2560                // per-bucket edge capacity (mean 2048, +11 sigma)
#define CHUNK 2048                // edges per bin block (14.3KB LDS, grid 1173)
#define NCH   391                 // ceil(EE/CHUNK)
#define NPB   3125                // NN/16 pull blocks per relation
#define ALPHA_ 0.5f
#define SLOPE_ 0.01f
#define BETA1_ 0.6931471805599453f   // log(2)
#define BETA2_ 0.4054651081081644f   // log(1.5)

typedef __attribute__((ext_vector_type(8))) short short8;   // 8 bf16 = 4 VGPRs
typedef __attribute__((ext_vector_type(4))) float f32x4;

__device__ __forceinline__ unsigned short f2b(float f) {   // fp32 -> bf16 RNE
    unsigned int u = __builtin_bit_cast(unsigned int, f);
    u += 0x7FFFu + ((u >> 16) & 1u);
    return (unsigned short)(u >> 16);
}
__device__ __forceinline__ unsigned int pack2(float lo, float hi) {
    return (unsigned int)f2b(lo) | ((unsigned int)f2b(hi) << 16);
}
__device__ __forceinline__ float blo(unsigned int w) { return __builtin_bit_cast(float, w << 16); }
__device__ __forceinline__ float bhi(unsigned int w) { return __builtin_bit_cast(float, w & 0xFFFF0000u); }

// ---------------- binning: bucket-sort edges by dst>>7 with LDS staging ----------------
// staging word: src(16b) | dlocal(7b) | bucket(9b)
__global__ __launch_bounds__(256) void bin_kernel(
    const int* __restrict__ src, const int* __restrict__ dst,
    int* __restrict__ cnt_out, int* __restrict__ bcnt, int* __restrict__ pairs)
{
    __shared__ int hist[NBK];
    __shared__ int lbase[NBK];
    __shared__ int gdelta[NBK];
    __shared__ int lcur[NBK];
    __shared__ unsigned int staging[CHUNK];
    const int tid = threadIdx.x;
    const int r = blockIdx.x / NCH;
    const int chunk = blockIdx.x % NCH;
    const int e0 = chunk * CHUNK;
    const int n = min(CHUNK, EE - e0);
    const int* sp = src + (size_t)r * EE + e0;
    const int* dp = dst + (size_t)r * EE + e0;

    for (int i = tid; i < NBK; i += 256) hist[i] = 0;
    __syncthreads();
    for (int i = tid; i < n; i += 256) {
        atomicAdd(&hist[dp[i] >> 7], 1);
        atomicAdd(&cnt_out[r * NN + sp[i]], 1);
    }
    __syncthreads();
    if (tid < 64) {
        int carry = 0;
        for (int c0 = 0; c0 < NBK; c0 += 64) {
            const int idx = c0 + tid;
            const int v = (idx < NBK) ? hist[idx] : 0;
            int incl = v;
            #pragma unroll
            for (int d = 1; d < 64; d <<= 1) {
                const int t = __shfl_up(incl, d, 64);
                if (tid >= d) incl += t;
            }
            if (idx < NBK) lbase[idx] = carry + incl - v;
            carry += __shfl(incl, 63, 64);
        }
    }
    __syncthreads();
    for (int b = tid; b < NBK; b += 256) {
        lcur[b] = lbase[b];
        const int h = hist[b];
        if (h > 0) {
            const int gstart = (r * NBK + b) * CAP + atomicAdd(&bcnt[r * NBK + b], h);
            gdelta[b] = gstart - lbase[b];
        }
    }
    __syncthreads();
    for (int i = tid; i < n; i += 256) {
        const int d = dp[i];
        const int b = d >> 7;
        const int pos = atomicAdd(&lcur[b], 1);
        staging[pos] = (unsigned int)sp[i] | ((unsigned int)(d & 127) << 16)
                     | ((unsigned int)b << 23);
    }
    __syncthreads();
    for (int j = tid; j < n; j += 256) {
        const unsigned int v = staging[j];
        const int b = v >> 23;
        const int gi = gdelta[b] + j;
        const int lo = gi - (r * NBK + b) * CAP;
        if (lo < CAP) pairs[gi] = (int)(v & 0x7FFFFF);
    }
}

// ---------------- per-bucket counting sort (in-place) -> CSR + off + cnt + degi ----------------
__global__ __launch_bounds__(256) void bucket_sort_kernel(
    int* __restrict__ pairs, const int* __restrict__ bcnt,
    int* __restrict__ off_g, int* __restrict__ cnt_g, float* __restrict__ degi_r)
{
    __shared__ int stage[CAP];
    __shared__ int cnt[BKT];
    __shared__ int base[BKT];
    __shared__ int pos[BKT];
    const int tid = threadIdx.x;
    const int bid = blockIdx.x;              // r*NBK + b
    const int n = min(bcnt[bid], CAP);
    int* pp = pairs + (size_t)bid * CAP;
    if (tid < BKT) cnt[tid] = 0;
    __syncthreads();
    for (int i = tid; i < n; i += 256) {
        const int p = pp[i];
        stage[i] = p;
        atomicAdd(&cnt[p >> 16], 1);
    }
    __syncthreads();
    if (tid < 64) {
        int carry = 0;
        for (int c0 = 0; c0 < BKT; c0 += 64) {
            const int v = cnt[c0 + tid];
            int incl = v;
            #pragma unroll
            for (int d = 1; d < 64; d <<= 1) {
                const int t = __shfl_up(incl, d, 64);
                if (tid >= d) incl += t;
            }
            base[c0 + tid] = carry + incl - v;
            carry += __shfl(incl, 63, 64);
        }
    }
    __syncthreads();
    if (tid < BKT) {
        pos[tid] = base[tid];
        const int r = bid / NBK;
        const int g = (bid % NBK) * BKT + tid;
        if (g < NN) {
            off_g[r * NN + g] = bid * CAP + base[tid];
            cnt_g[r * NN + g] = cnt[tid];
            degi_r[r * NN + g] = rsqrtf((float)max(cnt[tid], 1));
        }
    }
    __syncthreads();
    for (int i = tid; i < n; i += 256) {
        const int p = stage[i];
        const int q = atomicAdd(&pos[p >> 16], 1);
        pp[q] = p & 0xFFFF;                  // src index only (fits 16 bits)
    }
}

// ---------------- setup: dego-norm + x cast + W' prep (merged elementwise) ----------------
__global__ __launch_bounds__(256) void setup_kernel(
    const int* __restrict__ cnt_out, float* __restrict__ dego_r,
    const float* __restrict__ x, unsigned short* __restrict__ xb,
    const float* __restrict__ W1, const float* __restrict__ W2,
    const float* __restrict__ Wlin, unsigned short* __restrict__ Wt1,
    unsigned short* __restrict__ Wt2, unsigned short* __restrict__ WlT)
{
    const int i = blockIdx.x * 256 + threadIdx.x;   // 0 .. NN*DD/4-1 (1.6M)
    {   // cast x -> bf16 (full range)
        const float4 v = ((const float4*)x)[i];
        ushort4 o;
        o.x = f2b(v.x); o.y = f2b(v.y); o.z = f2b(v.z); o.w = f2b(v.w);
        ((ushort4*)xb)[i] = o;
    }
    if (i < RR * NN)
        dego_r[i] = rsqrtf((float)max(cnt_out[i], 1));
    if (i < RR * DD * DD) {
        const int r = i >> 14, rem = i & 16383, nn = rem >> 7, k = rem & 127;
        const float diag = (k == nn) ? 1.0f : 0.0f;
        const float w1 = W1[r * DD * DD + k * DD + nn];
        Wt1[i] = f2b(BETA1_ * w1 + diag * (1.0f - BETA1_));
        const float w2 = W2[r * DD * DD + k * DD + nn];
        Wt2[i] = f2b((BETA2_ * w2 + diag * (1.0f - BETA2_)) * (1.0f / 3.0f));
    } else if (i < RR * DD * DD + OUTD * DD) {
        const int j = i - RR * DD * DD;
        const int nn = j >> 7, k = j & 127;
        WlT[j] = f2b(Wlin[k * OUTD + nn]);
    }
}

// ---------------- merged pull (all 3 relations): bf16 gather + normalize + residual ----------------
// 16 lanes per dst node; unroll-4 with index prefetch for MLP depth.
__global__ __launch_bounds__(256) void pull_all_kernel(
    const unsigned short* __restrict__ hb,   // gather table [N,128] bf16
    const unsigned short* __restrict__ xb,   // residual [N,128] bf16
    const int* __restrict__ pairs, const int* __restrict__ off_g,
    const int* __restrict__ cnt_g, const float* __restrict__ dego_r,
    const float* __restrict__ degi_r, unsigned short* __restrict__ aggb)
{
    const int blk = blockIdx.x;              // r*NPB + nb
    const int r = blk / NPB;
    const int node = (blk % NPB) * 16 + (threadIdx.x >> 4);
    const int lane = threadIdx.x & 15;
    const int gi = r * NN + node;
    const int j0 = off_g[gi];
    const int j1 = j0 + cnt_g[gi];
    const float* dego = dego_r + (size_t)r * NN;
    const uint4* hb4 = (const uint4*)hb;
    float a0 = 0.f, a1 = 0.f, a2 = 0.f, a3 = 0.f, a4 = 0.f, a5 = 0.f, a6 = 0.f, a7 = 0.f;
    int j = j0;
    for (; j + 4 <= j1; j += 4) {
        const int s0 = pairs[j], s1 = pairs[j + 1], s2 = pairs[j + 2], s3 = pairs[j + 3];
        const float n0 = dego[s0], n1 = dego[s1], n2 = dego[s2], n3 = dego[s3];
        const uint4 q0 = hb4[(size_t)s0 * 16 + lane];
        const uint4 q1 = hb4[(size_t)s1 * 16 + lane];
        const uint4 q2 = hb4[(size_t)s2 * 16 + lane];
        const uint4 q3 = hb4[(size_t)s3 * 16 + lane];
        a0 += blo(q0.x) * n0 + blo(q1.x) * n1 + blo(q2.x) * n2 + blo(q3.x) * n3;
        a1 += bhi(q0.x) * n0 + bhi(q1.x) * n1 + bhi(q2.x) * n2 + bhi(q3.x) * n3;
        a2 += blo(q0.y) * n0 + blo(q1.y) * n1 + blo(q2.y) * n2 + blo(q3.y) * n3;
        a3 += bhi(q0.y) * n0 + bhi(q1.y) * n1 + bhi(q2.y) * n2 + bhi(q3.y) * n3;
        a4 += blo(q0.z) * n0 + blo(q1.z) * n1 + blo(q2.z) * n2 + blo(q3.z) * n3;
        a5 += bhi(q0.z) * n0 + bhi(q1.z) * n1 + bhi(q2.z) * n2 + bhi(q3.z) * n3;
        a6 += blo(q0.w) * n0 + blo(q1.w) * n1 + blo(q2.w) * n2 + blo(q3.w) * n3;
        a7 += bhi(q0.w) * n0 + bhi(q1.w) * n1 + bhi(q2.w) * n2 + bhi(q3.w) * n3;
    }
    for (; j < j1; ++j) {
        const int s0 = pairs[j];
        const float n0 = dego[s0];
        const uint4 q0 = hb4[(size_t)s0 * 16 + lane];
        a0 += blo(q0.x) * n0; a1 += bhi(q0.x) * n0;
        a2 += blo(q0.y) * n0; a3 += bhi(q0.y) * n0;
        a4 += blo(q0.z) * n0; a5 += bhi(q0.z) * n0;
        a6 += blo(q0.w) * n0; a7 += bhi(q0.w) * n0;
    }
    const float nd = degi_r[gi] * (1.0f - ALPHA_);
    const uint4 xq = ((const uint4*)xb)[(size_t)node * 16 + lane];
    uint4 o;
    o.x = pack2(a0 * nd + ALPHA_ * blo(xq.x), a1 * nd + ALPHA_ * bhi(xq.x));
    o.y = pack2(a2 * nd + ALPHA_ * blo(xq.y), a3 * nd + ALPHA_ * bhi(xq.y));
    o.z = pack2(a4 * nd + ALPHA_ * blo(xq.z), a5 * nd + ALPHA_ * bhi(xq.z));
    o.w = pack2(a6 * nd + ALPHA_ * blo(xq.w), a7 * nd + ALPHA_ * bhi(xq.w));
    ((uint4*)aggb)[(size_t)gi * 16 + lane] = o;
}

// ---------------- MFMA conv: rst_r @ W'_r (+bias-init) [+leaky] summed over r ----------------
template<int LIN>
__global__ __launch_bounds__(256) void conv_mfma_kernel(
    const unsigned short* __restrict__ aggb,   // [R][N][128] bf16
    const unsigned short* __restrict__ WtG,    // [R][128][128] bf16, [n][k]
    const float* __restrict__ bias,            // [R,128]
    const unsigned short* __restrict__ WlT,    // [64][128] bf16 (LIN)
    const float* __restrict__ blin,            // [64] (LIN)
    unsigned short* __restrict__ houtb,        // h1b (LIN=0)
    float* __restrict__ outf)                  // out [N,64] (LIN=1)
{
    __shared__ unsigned short WtL[DD * 136];   // 34816 B, stride 136 bf16 (17 uint4)
    uint4* WtL4 = (uint4*)WtL;
    const int tid  = threadIdx.x;
    const int wave = tid >> 6;
    const int lane = tid & 63;
    const int l15  = lane & 15;
    const int q    = lane >> 4;                // 0..3
    const int blockRow = blockIdx.x * 64;
    const int row0 = blockRow + wave * 16;
    const int arow = min(row0 + l15, NN - 1);  // A-frag row (clamped; OOB rows not stored)

    f32x4 o[8];
    if (LIN) {
        #pragma unroll
        for (int ct = 0; ct < 8; ++ct) {
            const int col = ct * 16 + l15;
            const float bv = (bias[col] + bias[DD + col] + bias[2 * DD + col]) * (1.0f / 3.0f);
            o[ct] = (f32x4){bv, bv, bv, bv};
        }
    } else {
        #pragma unroll
        for (int ct = 0; ct < 8; ++ct) o[ct] = (f32x4){0.f, 0.f, 0.f, 0.f};
    }

    for (int r = 0; r < RR; ++r) {
        __syncthreads();
        const uint4* wg = (const uint4*)(WtG + (size_t)r * DD * DD);
        for (int i = tid; i < DD * 16; i += 256)
            WtL4[(i >> 4) * 17 + (i & 15)] = wg[i];
        __syncthreads();

        short8 a[4];
        const uint4* ap = (const uint4*)aggb + ((size_t)r * NN + arow) * 16 + q;
        #pragma unroll
        for (int ks = 0; ks < 4; ++ks)
            a[ks] = __builtin_bit_cast(short8, ap[ks * 4]);

        #pragma unroll
        for (int ct = 0; ct < 8; ++ct) {
            f32x4 acc;
            if (LIN) {
                acc = o[ct];
            } else {
                const float bv = bias[r * DD + ct * 16 + l15];
                acc = (f32x4){bv, bv, bv, bv};
            }
            const int nrow = ct * 16 + l15;
            #pragma unroll
            for (int ks = 0; ks < 4; ++ks) {
                const short8 b = __builtin_bit_cast(short8, WtL4[nrow * 17 + ks * 4 + q]);
                acc = __builtin_amdgcn_mfma_f32_16x16x32_bf16(a[ks], b, acc, 0, 0, 0);
            }
            if (LIN) {
                o[ct] = acc;
            } else {
                #pragma unroll
                for (int e = 0; e < 4; ++e) {
                    float v = acc[e];
                    v = v >= 0.f ? v : SLOPE_ * v;
                    o[ct][e] += v * (1.0f / 3.0f);
                }
            }
        }
    }

    __syncthreads();
    unsigned short* tile = WtL;                // rows 0..63, stride 136
    #pragma unroll
    for (int ct = 0; ct < 8; ++ct) {
        const int col = ct * 16 + l15;
        #pragma unroll
        for (int e = 0; e < 4; ++e) {
            const int lrow = wave * 16 + q * 4 + e;
            tile[lrow * 136 + col] = f2b(o[ct][e]);
        }
    }
    if (LIN) {
        uint4* wl4 = WtL4 + 64 * 17;
        const uint4* wg = (const uint4*)WlT;
        for (int i = tid; i < OUTD * 16; i += 256)
            wl4[(i >> 4) * 17 + (i & 15)] = wg[i];
    }
    __syncthreads();

    if (!LIN) {
        for (int i = tid; i < 64 * 16; i += 256) {
            const int lrow = i >> 4, c = i & 15;
            const int grow = blockRow + lrow;
            if (grow < NN)
                ((uint4*)houtb)[(size_t)grow * 16 + c] = WtL4[lrow * 17 + c];
        }
    } else {
        short8 a2[4];
        const int lrow = wave * 16 + l15;
        #pragma unroll
        for (int ks = 0; ks < 4; ++ks)
            a2[ks] = __builtin_bit_cast(short8, WtL4[lrow * 17 + ks * 4 + q]);
        #pragma unroll
        for (int ct = 0; ct < 4; ++ct) {
            const int col = ct * 16 + l15;
            const float bv = blin[col];
            f32x4 acc = (f32x4){bv, bv, bv, bv};
            #pragma unroll
            for (int ks = 0; ks < 4; ++ks) {
                const short8 b = __builtin_bit_cast(short8, WtL4[(64 + col) * 17 + ks * 4 + q]);
                acc = __builtin_amdgcn_mfma_f32_16x16x32_bf16(a2[ks], b, acc, 0, 0, 0);
            }
            #pragma unroll
            for (int e = 0; e < 4; ++e) {
                const int grow = row0 + q * 4 + e;
                if (grow < NN) outf[(size_t)grow * OUTD + col] = acc[e];
            }
        }
    }
}

extern "C" void kernel_launch(void* const* d_in, const int* in_sizes, int n_in,
                              void* d_out, int out_size, void* d_ws, size_t ws_size,
                              hipStream_t stream)
{
    const float* x    = (const float*)d_in[0];
    const int*   src  = (const int*)  d_in[1];
    const int*   dst  = (const int*)  d_in[2];
    const float* W1   = (const float*)d_in[3];
    const float* b1   = (const float*)d_in[4];
    const float* W2   = (const float*)d_in[5];
    const float* b2   = (const float*)d_in[6];
    const float* Wlin = (const float*)d_in[7];
    const float* blin = (const float*)d_in[8];
    float* out = (float*)d_out;

    // ws layout (4B units): cnt_out[3N] | bcnt[3*NBK] | dego_r[3N] | degi_r[3N] |
    //   off_g[3N] | cnt_g[3N] | pairs[3*NBK*CAP] | xb(bf16 N*D) | h1b(bf16 N*D) |
    //   aggb(bf16 3*N*D) | Wt1 | Wt2 | WlT                                ~= 80 MB
    int*   cnt_out = (int*)d_ws;
    int*   bcnt    = cnt_out + RR * NN;
    float* dego_r  = (float*)(bcnt + RR * NBK);
    float* degi_r  = dego_r + RR * NN;
    int*   off_g   = (int*)(degi_r + RR * NN);
    int*   cnt_g   = off_g + RR * NN;
    int*   pairs   = cnt_g + RR * NN;
    unsigned short* xb   = (unsigned short*)(pairs + (size_t)RR * NBK * CAP);
    unsigned short* h1b  = xb + (size_t)NN * DD;
    unsigned short* aggb = h1b + (size_t)NN * DD;
    unsigned short* Wt1  = aggb + (size_t)RR * NN * DD;
    unsigned short* Wt2  = Wt1 + RR * DD * DD;
    unsigned short* WlT  = Wt2 + RR * DD * DD;

    hipMemsetAsync(cnt_out, 0, (size_t)(RR * NN + RR * NBK) * sizeof(int), stream);

    const int gemm_blocks = (NN + 63) / 64;

    // ---- graph preprocessing (once; same graph both layers) ----
    bin_kernel<<<RR * NCH, 256, 0, stream>>>(src, dst, cnt_out, bcnt, pairs);
    setup_kernel<<<NN * DD / 4 / 256, 256, 0, stream>>>(
        cnt_out, dego_r, x, xb, W1, W2, Wlin, Wt1, Wt2, WlT);
    bucket_sort_kernel<<<RR * NBK, 256, 0, stream>>>(pairs, bcnt, off_g, cnt_g, degi_r);

    // ---- conv1: h1b = bf16( mean_r leaky( rst_r @ W1'_r + b1_r ) ) ----
    pull_all_kernel<<<RR * NPB, 256, 0, stream>>>(
        xb, xb, pairs, off_g, cnt_g, dego_r, degi_r, aggb);
    conv_mfma_kernel<0><<<gemm_blocks, 256, 0, stream>>>(
        aggb, Wt1, b1, nullptr, nullptr, h1b, nullptr);

    // ---- conv2 (+ fused final linear): out = ( sum_r rst_r @ (W2'_r/3) + mean b2 ) @ Wlin + blin ----
    pull_all_kernel<<<RR * NPB, 256, 0, stream>>>(
        h1b, xb, pairs, off_g, cnt_g, dego_r, degi_r, aggb);
    conv_mfma_kernel<1><<<gemm_blocks, 256, 0, stream>>>(
        aggb, Wt2, b2, WlT, blin, nullptr, out);
}

// Round 8
// 416.190 us; speedup vs baseline: 10.6875x; 1.1373x over previous
//
#include <hip/hip_runtime.h>

#define NN    50000
#define DD    128
#define RR    3
#define EE    800000
#define OUTD  64
#define BKT   128                 // nodes per bucket (dst and src binning)
#define NBK   391                 // ceil(NN/BKT)
#define CAP   2560                // per-bucket edge capacity, 4B dst-entries
#define CAPB  2560                // per-bucket edge capacity, 2B src-entries
#define CHUNK 2048                // edges per bin block
#define NCH   391                 // ceil(EE/CHUNK)
#define NPB   3125                // NN/16 pull blocks per relation
#define ALPHA_ 0.5f
#define SLOPE_ 0.01f
#define BETA1_ 0.6931471805599453f   // log(2)
#define BETA2_ 0.4054651081081644f   // log(1.5)

typedef __attribute__((ext_vector_type(8))) short short8;   // 8 bf16 = 4 VGPRs
typedef __attribute__((ext_vector_type(4))) float f32x4;

__device__ __forceinline__ unsigned short f2b(float f) {   // fp32 -> bf16 RNE
    unsigned int u = __builtin_bit_cast(unsigned int, f);
    u += 0x7FFFu + ((u >> 16) & 1u);
    return (unsigned short)(u >> 16);
}
__device__ __forceinline__ unsigned int pack2(float lo, float hi) {
    return (unsigned int)f2b(lo) | ((unsigned int)f2b(hi) << 16);
}
__device__ __forceinline__ float blo(unsigned int w) { return __builtin_bit_cast(float, w << 16); }
__device__ __forceinline__ float bhi(unsigned int w) { return __builtin_bit_cast(float, w & 0xFFFF0000u); }

// ---------------- binning: two LDS bucket-sort phases (by dst>>7, then by src>>7) ----------------
// NO per-edge global atomics. Phase A payload: src(16)|dlocal(7)|bucket(9).
// Phase B payload (ushort): bucket(9)<<7 | slocal(7).
__global__ __launch_bounds__(256) void bin_kernel(
    const int* __restrict__ src, const int* __restrict__ dst,
    int* __restrict__ bcnt_d, int* __restrict__ bcnt_s,
    int* __restrict__ pairs_d, unsigned short* __restrict__ pairs_s)
{
    __shared__ int hist[NBK];
    __shared__ int lbase[NBK];
    __shared__ int gdelta[NBK];
    __shared__ int lcur[NBK];
    __shared__ unsigned int staging[CHUNK];
    unsigned short* staging16 = (unsigned short*)staging;
    const int tid = threadIdx.x;
    const int r = blockIdx.x / NCH;
    const int chunk = blockIdx.x % NCH;
    const int e0 = chunk * CHUNK;
    const int n = min(CHUNK, EE - e0);
    const int* sp = src + (size_t)r * EE + e0;
    const int* dp = dst + (size_t)r * EE + e0;

    // ================= phase A: bin by dst>>7 =================
    for (int i = tid; i < NBK; i += 256) hist[i] = 0;
    __syncthreads();
    for (int i = tid; i < n; i += 256)
        atomicAdd(&hist[dp[i] >> 7], 1);
    __syncthreads();
    if (tid < 64) {
        int carry = 0;
        for (int c0 = 0; c0 < NBK; c0 += 64) {
            const int idx = c0 + tid;
            const int v = (idx < NBK) ? hist[idx] : 0;
            int incl = v;
            #pragma unroll
            for (int d = 1; d < 64; d <<= 1) {
                const int t = __shfl_up(incl, d, 64);
                if (tid >= d) incl += t;
            }
            if (idx < NBK) lbase[idx] = carry + incl - v;
            carry += __shfl(incl, 63, 64);
        }
    }
    __syncthreads();
    for (int b = tid; b < NBK; b += 256) {
        lcur[b] = lbase[b];
        const int h = hist[b];
        if (h > 0) {
            const int gstart = (r * NBK + b) * CAP + atomicAdd(&bcnt_d[r * NBK + b], h);
            gdelta[b] = gstart - lbase[b];
        }
    }
    __syncthreads();
    for (int i = tid; i < n; i += 256) {
        const int d = dp[i];
        const int b = d >> 7;
        const int pos = atomicAdd(&lcur[b], 1);
        staging[pos] = (unsigned int)sp[i] | ((unsigned int)(d & 127) << 16)
                     | ((unsigned int)b << 23);
    }
    __syncthreads();
    for (int j = tid; j < n; j += 256) {
        const unsigned int v = staging[j];
        const int b = v >> 23;
        const int gi = gdelta[b] + j;
        const int lo = gi - (r * NBK + b) * CAP;
        if (lo < CAP) pairs_d[gi] = (int)(v & 0x7FFFFF);
    }
    __syncthreads();

    // ================= phase B: bin by src>>7 (for out-degree counting) =================
    for (int i = tid; i < NBK; i += 256) hist[i] = 0;
    __syncthreads();
    for (int i = tid; i < n; i += 256)
        atomicAdd(&hist[sp[i] >> 7], 1);
    __syncthreads();
    if (tid < 64) {
        int carry = 0;
        for (int c0 = 0; c0 < NBK; c0 += 64) {
            const int idx = c0 + tid;
            const int v = (idx < NBK) ? hist[idx] : 0;
            int incl = v;
            #pragma unroll
            for (int d = 1; d < 64; d <<= 1) {
                const int t = __shfl_up(incl, d, 64);
                if (tid >= d) incl += t;
            }
            if (idx < NBK) lbase[idx] = carry + incl - v;
            carry += __shfl(incl, 63, 64);
        }
    }
    __syncthreads();
    for (int b = tid; b < NBK; b += 256) {
        lcur[b] = lbase[b];
        const int h = hist[b];
        if (h > 0) {
            const int gstart = (r * NBK + b) * CAPB + atomicAdd(&bcnt_s[r * NBK + b], h);
            gdelta[b] = gstart - lbase[b];
        }
    }
    __syncthreads();
    for (int i = tid; i < n; i += 256) {
        const int s = sp[i];
        const int b = s >> 7;
        const int pos = atomicAdd(&lcur[b], 1);
        staging16[pos] = (unsigned short)((b << 7) | (s & 127));
    }
    __syncthreads();
    for (int j = tid; j < n; j += 256) {
        const unsigned short v = staging16[j];
        const int b = v >> 7;
        const int gi = gdelta[b] + j;
        const int lo = gi - (r * NBK + b) * CAPB;
        if (lo < CAPB) pairs_s[gi] = v;
    }
}

// ---------------- per-bucket: dst counting-sort -> CSR + degi, src count -> dego ----------------
__global__ __launch_bounds__(256) void sort_count_kernel(
    int* __restrict__ pairs_d, const unsigned short* __restrict__ pairs_s,
    const int* __restrict__ bcnt_d, const int* __restrict__ bcnt_s,
    int* __restrict__ off_g, int* __restrict__ cnt_g,
    float* __restrict__ degi_r, float* __restrict__ dego_r)
{
    __shared__ int stage[CAP];
    __shared__ int cnt[BKT];
    __shared__ int base[BKT];
    __shared__ int pos[BKT];
    __shared__ int scnt[BKT];
    const int tid = threadIdx.x;
    const int bid = blockIdx.x;              // r*NBK + b
    const int n = min(bcnt_d[bid], CAP);
    const int n2 = min(bcnt_s[bid], CAPB);
    int* pp = pairs_d + (size_t)bid * CAP;
    const unsigned short* ps = pairs_s + (size_t)bid * CAPB;
    if (tid < BKT) { cnt[tid] = 0; scnt[tid] = 0; }
    __syncthreads();
    for (int i = tid; i < n; i += 256) {
        const int p = pp[i];
        stage[i] = p;
        atomicAdd(&cnt[p >> 16], 1);
    }
    for (int i = tid; i < n2; i += 256)
        atomicAdd(&scnt[ps[i] & 127], 1);
    __syncthreads();
    if (tid < 64) {
        int carry = 0;
        for (int c0 = 0; c0 < BKT; c0 += 64) {
            const int v = cnt[c0 + tid];
            int incl = v;
            #pragma unroll
            for (int d = 1; d < 64; d <<= 1) {
                const int t = __shfl_up(incl, d, 64);
                if (tid >= d) incl += t;
            }
            base[c0 + tid] = carry + incl - v;
            carry += __shfl(incl, 63, 64);
        }
    }
    __syncthreads();
    if (tid < BKT) {
        pos[tid] = base[tid];
        const int r = bid / NBK;
        const int g = (bid % NBK) * BKT + tid;
        if (g < NN) {
            off_g[r * NN + g] = bid * CAP + base[tid];
            cnt_g[r * NN + g] = cnt[tid];
            degi_r[r * NN + g] = rsqrtf((float)max(cnt[tid], 1));
            dego_r[r * NN + g] = rsqrtf((float)max(scnt[tid], 1));
        }
    }
    __syncthreads();
    for (int i = tid; i < n; i += 256) {
        const int p = stage[i];
        const int q = atomicAdd(&pos[p >> 16], 1);
        pp[q] = p & 0xFFFF;                  // src index only (fits 16 bits)
    }
}

// ---------------- setup: x cast + W' prep (merged elementwise) ----------------
__global__ __launch_bounds__(256) void setup_kernel(
    const float* __restrict__ x, unsigned short* __restrict__ xb,
    const float* __restrict__ W1, const float* __restrict__ W2,
    const float* __restrict__ Wlin, unsigned short* __restrict__ Wt1,
    unsigned short* __restrict__ Wt2, unsigned short* __restrict__ WlT)
{
    const int i = blockIdx.x * 256 + threadIdx.x;   // 0 .. NN*DD/4-1 (1.6M)
    {   // cast x -> bf16 (full range)
        const float4 v = ((const float4*)x)[i];
        ushort4 o;
        o.x = f2b(v.x); o.y = f2b(v.y); o.z = f2b(v.z); o.w = f2b(v.w);
        ((ushort4*)xb)[i] = o;
    }
    if (i < RR * DD * DD) {
        const int r = i >> 14, rem = i & 16383, nn = rem >> 7, k = rem & 127;
        const float diag = (k == nn) ? 1.0f : 0.0f;
        const float w1 = W1[r * DD * DD + k * DD + nn];
        Wt1[i] = f2b(BETA1_ * w1 + diag * (1.0f - BETA1_));
        const float w2 = W2[r * DD * DD + k * DD + nn];
        Wt2[i] = f2b((BETA2_ * w2 + diag * (1.0f - BETA2_)) * (1.0f / 3.0f));
    } else if (i < RR * DD * DD + OUTD * DD) {
        const int j = i - RR * DD * DD;
        const int nn = j >> 7, k = j & 127;
        WlT[j] = f2b(Wlin[k * OUTD + nn]);
    }
}

// ---------------- merged pull (all 3 relations): bf16 gather + normalize + residual ----------------
// 16 lanes per dst node; unroll-4 with index prefetch for MLP depth.
__global__ __launch_bounds__(256) void pull_all_kernel(
    const unsigned short* __restrict__ hb,   // gather table [N,128] bf16
    const unsigned short* __restrict__ xb,   // residual [N,128] bf16
    const int* __restrict__ pairs, const int* __restrict__ off_g,
    const int* __restrict__ cnt_g, const float* __restrict__ dego_r,
    const float* __restrict__ degi_r, unsigned short* __restrict__ aggb)
{
    const int blk = blockIdx.x;              // r*NPB + nb
    const int r = blk / NPB;
    const int node = (blk % NPB) * 16 + (threadIdx.x >> 4);
    const int lane = threadIdx.x & 15;
    const int gi = r * NN + node;
    const int j0 = off_g[gi];
    const int j1 = j0 + cnt_g[gi];
    const float* dego = dego_r + (size_t)r * NN;
    const uint4* hb4 = (const uint4*)hb;
    float a0 = 0.f, a1 = 0.f, a2 = 0.f, a3 = 0.f, a4 = 0.f, a5 = 0.f, a6 = 0.f, a7 = 0.f;
    int j = j0;
    for (; j + 4 <= j1; j += 4) {
        const int s0 = pairs[j], s1 = pairs[j + 1], s2 = pairs[j + 2], s3 = pairs[j + 3];
        const float n0 = dego[s0], n1 = dego[s1], n2 = dego[s2], n3 = dego[s3];
        const uint4 q0 = hb4[(size_t)s0 * 16 + lane];
        const uint4 q1 = hb4[(size_t)s1 * 16 + lane];
        const uint4 q2 = hb4[(size_t)s2 * 16 + lane];
        const uint4 q3 = hb4[(size_t)s3 * 16 + lane];
        a0 += blo(q0.x) * n0 + blo(q1.x) * n1 + blo(q2.x) * n2 + blo(q3.x) * n3;
        a1 += bhi(q0.x) * n0 + bhi(q1.x) * n1 + bhi(q2.x) * n2 + bhi(q3.x) * n3;
        a2 += blo(q0.y) * n0 + blo(q1.y) * n1 + blo(q2.y) * n2 + blo(q3.y) * n3;
        a3 += bhi(q0.y) * n0 + bhi(q1.y) * n1 + bhi(q2.y) * n2 + bhi(q3.y) * n3;
        a4 += blo(q0.z) * n0 + blo(q1.z) * n1 + blo(q2.z) * n2 + blo(q3.z) * n3;
        a5 += bhi(q0.z) * n0 + bhi(q1.z) * n1 + bhi(q2.z) * n2 + bhi(q3.z) * n3;
        a6 += blo(q0.w) * n0 + blo(q1.w) * n1 + blo(q2.w) * n2 + blo(q3.w) * n3;
        a7 += bhi(q0.w) * n0 + bhi(q1.w) * n1 + bhi(q2.w) * n2 + bhi(q3.w) * n3;
    }
    for (; j < j1; ++j) {
        const int s0 = pairs[j];
        const float n0 = dego[s0];
        const uint4 q0 = hb4[(size_t)s0 * 16 + lane];
        a0 += blo(q0.x) * n0; a1 += bhi(q0.x) * n0;
        a2 += blo(q0.y) * n0; a3 += bhi(q0.y) * n0;
        a4 += blo(q0.z) * n0; a5 += bhi(q0.z) * n0;
        a6 += blo(q0.w) * n0; a7 += bhi(q0.w) * n0;
    }
    const float nd = degi_r[gi] * (1.0f - ALPHA_);
    const uint4 xq = ((const uint4*)xb)[(size_t)node * 16 + lane];
    uint4 o;
    o.x = pack2(a0 * nd + ALPHA_ * blo(xq.x), a1 * nd + ALPHA_ * bhi(xq.x));
    o.y = pack2(a2 * nd + ALPHA_ * blo(xq.y), a3 * nd + ALPHA_ * bhi(xq.y));
    o.z = pack2(a4 * nd + ALPHA_ * blo(xq.z), a5 * nd + ALPHA_ * bhi(xq.z));
    o.w = pack2(a6 * nd + ALPHA_ * blo(xq.w), a7 * nd + ALPHA_ * bhi(xq.w));
    ((uint4*)aggb)[(size_t)gi * 16 + lane] = o;
}

// ---------------- MFMA conv: rst_r @ W'_r (+bias-init) [+leaky] summed over r ----------------
template<int LIN>
__global__ __launch_bounds__(256) void conv_mfma_kernel(
    const unsigned short* __restrict__ aggb,   // [R][N][128] bf16
    const unsigned short* __restrict__ WtG,    // [R][128][128] bf16, [n][k]
    const float* __restrict__ bias,            // [R,128]
    const unsigned short* __restrict__ WlT,    // [64][128] bf16 (LIN)
    const float* __restrict__ blin,            // [64] (LIN)
    unsigned short* __restrict__ houtb,        // h1b (LIN=0)
    float* __restrict__ outf)                  // out [N,64] (LIN=1)
{
    __shared__ unsigned short WtL[DD * 136];   // 34816 B, stride 136 bf16 (17 uint4)
    uint4* WtL4 = (uint4*)WtL;
    const int tid  = threadIdx.x;
    const int wave = tid >> 6;
    const int lane = tid & 63;
    const int l15  = lane & 15;
    const int q    = lane >> 4;                // 0..3
    const int blockRow = blockIdx.x * 64;
    const int row0 = blockRow + wave * 16;
    const int arow = min(row0 + l15, NN - 1);  // A-frag row (clamped; OOB rows not stored)

    f32x4 o[8];
    if (LIN) {
        #pragma unroll
        for (int ct = 0; ct < 8; ++ct) {
            const int col = ct * 16 + l15;
            const float bv = (bias[col] + bias[DD + col] + bias[2 * DD + col]) * (1.0f / 3.0f);
            o[ct] = (f32x4){bv, bv, bv, bv};
        }
    } else {
        #pragma unroll
        for (int ct = 0; ct < 8; ++ct) o[ct] = (f32x4){0.f, 0.f, 0.f, 0.f};
    }

    for (int r = 0; r < RR; ++r) {
        __syncthreads();
        const uint4* wg = (const uint4*)(WtG + (size_t)r * DD * DD);
        for (int i = tid; i < DD * 16; i += 256)
            WtL4[(i >> 4) * 17 + (i & 15)] = wg[i];
        __syncthreads();

        short8 a[4];
        const uint4* ap = (const uint4*)aggb + ((size_t)r * NN + arow) * 16 + q;
        #pragma unroll
        for (int ks = 0; ks < 4; ++ks)
            a[ks] = __builtin_bit_cast(short8, ap[ks * 4]);

        #pragma unroll
        for (int ct = 0; ct < 8; ++ct) {
            f32x4 acc;
            if (LIN) {
                acc = o[ct];
            } else {
                const float bv = bias[r * DD + ct * 16 + l15];
                acc = (f32x4){bv, bv, bv, bv};
            }
            const int nrow = ct * 16 + l15;
            #pragma unroll
            for (int ks = 0; ks < 4; ++ks) {
                const short8 b = __builtin_bit_cast(short8, WtL4[nrow * 17 + ks * 4 + q]);
                acc = __builtin_amdgcn_mfma_f32_16x16x32_bf16(a[ks], b, acc, 0, 0, 0);
            }
            if (LIN) {
                o[ct] = acc;
            } else {
                #pragma unroll
                for (int e = 0; e < 4; ++e) {
                    float v = acc[e];
                    v = v >= 0.f ? v : SLOPE_ * v;
                    o[ct][e] += v * (1.0f / 3.0f);
                }
            }
        }
    }

    __syncthreads();
    unsigned short* tile = WtL;                // rows 0..63, stride 136
    #pragma unroll
    for (int ct = 0; ct < 8; ++ct) {
        const int col = ct * 16 + l15;
        #pragma unroll
        for (int e = 0; e < 4; ++e) {
            const int lrow = wave * 16 + q * 4 + e;
            tile[lrow * 136 + col] = f2b(o[ct][e]);
        }
    }
    if (LIN) {
        uint4* wl4 = WtL4 + 64 * 17;
        const uint4* wg = (const uint4*)WlT;
        for (int i = tid; i < OUTD * 16; i += 256)
            wl4[(i >> 4) * 17 + (i & 15)] = wg[i];
    }
    __syncthreads();

    if (!LIN) {
        for (int i = tid; i < 64 * 16; i += 256) {
            const int lrow = i >> 4, c = i & 15;
            const int grow = blockRow + lrow;
            if (grow < NN)
                ((uint4*)houtb)[(size_t)grow * 16 + c] = WtL4[lrow * 17 + c];
        }
    } else {
        short8 a2[4];
        const int lrow = wave * 16 + l15;
        #pragma unroll
        for (int ks = 0; ks < 4; ++ks)
            a2[ks] = __builtin_bit_cast(short8, WtL4[lrow * 17 + ks * 4 + q]);
        #pragma unroll
        for (int ct = 0; ct < 4; ++ct) {
            const int col = ct * 16 + l15;
            const float bv = blin[col];
            f32x4 acc = (f32x4){bv, bv, bv, bv};
            #pragma unroll
            for (int ks = 0; ks < 4; ++ks) {
                const short8 b = __builtin_bit_cast(short8, WtL4[(64 + col) * 17 + ks * 4 + q]);
                acc = __builtin_amdgcn_mfma_f32_16x16x32_bf16(a2[ks], b, acc, 0, 0, 0);
            }
            #pragma unroll
            for (int e = 0; e < 4; ++e) {
                const int grow = row0 + q * 4 + e;
                if (grow < NN) outf[(size_t)grow * OUTD + col] = acc[e];
            }
        }
    }
}

extern "C" void kernel_launch(void* const* d_in, const int* in_sizes, int n_in,
                              void* d_out, int out_size, void* d_ws, size_t ws_size,
                              hipStream_t stream)
{
    const float* x    = (const float*)d_in[0];
    const int*   src  = (const int*)  d_in[1];
    const int*   dst  = (const int*)  d_in[2];
    const float* W1   = (const float*)d_in[3];
    const float* b1   = (const float*)d_in[4];
    const float* W2   = (const float*)d_in[5];
    const float* b2   = (const float*)d_in[6];
    const float* Wlin = (const float*)d_in[7];
    const float* blin = (const float*)d_in[8];
    float* out = (float*)d_out;

    // ws layout (4B units): bcnt_d[3*NBK] | bcnt_s[3*NBK] | dego_r[3N] | degi_r[3N] |
    //   off_g[3N] | cnt_g[3N] | pairs_d[3*NBK*CAP] | pairs_s(u16, 3*NBK*CAPB) |
    //   xb(bf16 N*D) | h1b(bf16 N*D) | aggb(bf16 3*N*D) | Wt1 | Wt2 | WlT     ~= 86 MB
    int*   bcnt_d  = (int*)d_ws;
    int*   bcnt_s  = bcnt_d + RR * NBK;
    float* dego_r  = (float*)(bcnt_s + RR * NBK);
    float* degi_r  = dego_r + RR * NN;
    int*   off_g   = (int*)(degi_r + RR * NN);
    int*   cnt_g   = off_g + RR * NN;
    int*   pairs_d = cnt_g + RR * NN;
    unsigned short* pairs_s = (unsigned short*)(pairs_d + (size_t)RR * NBK * CAP);
    unsigned short* xb   = pairs_s + (size_t)RR * NBK * CAPB;
    unsigned short* h1b  = xb + (size_t)NN * DD;
    unsigned short* aggb = h1b + (size_t)NN * DD;
    unsigned short* Wt1  = aggb + (size_t)RR * NN * DD;
    unsigned short* Wt2  = Wt1 + RR * DD * DD;
    unsigned short* WlT  = Wt2 + RR * DD * DD;

    hipMemsetAsync(bcnt_d, 0, (size_t)2 * RR * NBK * sizeof(int), stream);

    const int gemm_blocks = (NN + 63) / 64;

    // ---- graph preprocessing (once; same graph both layers) ----
    bin_kernel<<<RR * NCH, 256, 0, stream>>>(src, dst, bcnt_d, bcnt_s, pairs_d, pairs_s);
    setup_kernel<<<NN * DD / 4 / 256, 256, 0, stream>>>(
        x, xb, W1, W2, Wlin, Wt1, Wt2, WlT);
    sort_count_kernel<<<RR * NBK, 256, 0, stream>>>(
        pairs_d, pairs_s, bcnt_d, bcnt_s, off_g, cnt_g, degi_r, dego_r);

    // ---- conv1: h1b = bf16( mean_r leaky( rst_r @ W1'_r + b1_r ) ) ----
    pull_all_kernel<<<RR * NPB, 256, 0, stream>>>(
        xb, xb, pairs_d, off_g, cnt_g, dego_r, degi_r, aggb);
    conv_mfma_kernel<0><<<gemm_blocks, 256, 0, stream>>>(
        aggb, Wt1, b1, nullptr, nullptr, h1b, nullptr);

    // ---- conv2 (+ fused final linear): out = ( sum_r rst_r @ (W2'_r/3) + mean b2 ) @ Wlin + blin ----
    pull_all_kernel<<<RR * NPB, 256, 0, stream>>>(
        h1b, xb, pairs_d, off_g, cnt_g, dego_r, degi_r, aggb);
    conv_mfma_kernel<1><<<gemm_blocks, 256, 0, stream>>>(
        aggb, Wt2, b2, WlT, blin, nullptr, out);
}